// Round 6
// baseline (482.723 us; speedup 1.0000x reference)
//
#include <hip/hip_runtime.h>
#include <hip/hip_bf16.h>

typedef unsigned short u16;
typedef __attribute__((ext_vector_type(8))) short bf16x8;
typedef __attribute__((ext_vector_type(4))) float f32x4;
typedef __attribute__((ext_vector_type(4))) unsigned short u16x4;

#define NDIM 128
#define EDIM 32
#define HSTR 136     // gemm h LDS stride (u16): 16B aligned, 2-way banks (free)
#define NSPLIT 32    // stats atomic split copies

__device__ __forceinline__ float bf2f(u16 u) {
    union { unsigned int i; float f; } v; v.i = ((unsigned int)u) << 16; return v.f;
}
__device__ __forceinline__ u16 f2bf(float f) {
    __hip_bfloat16 h = __float2bfloat16(f);
    return *reinterpret_cast<u16*>(&h);
}

// ---------------------------------------------------------------------------
// K0: dtype detector (flag: 1 = bf16, 0 = fp32)
// ---------------------------------------------------------------------------
__global__ void detect_kernel(const void* __restrict__ x, int* __restrict__ flag) {
    __shared__ int cnt;
    if (threadIdx.x == 0) cnt = 0;
    __syncthreads();
    const u16* p = (const u16*)x;
    int crazy = 0;
    for (int i = threadIdx.x; i < 512; i += 64) {
        u16 v = p[2 * i];
        int e = (v >> 7) & 0xFF;
        if (e != 0 && (e < 100 || e > 150)) crazy++;
    }
    atomicAdd(&cnt, crazy);
    __syncthreads();
    if (threadIdx.x == 0) *flag = (cnt > 128) ? 0 : 1;
}

// ---------------------------------------------------------------------------
// CSR build: histogram -> coalesced 3-phase scan -> scatter
// ---------------------------------------------------------------------------
__global__ __launch_bounds__(256) void hist_kernel(
    const int* __restrict__ ei, int* __restrict__ cnt, int E) {
    int e = blockIdx.x * 256 + threadIdx.x;
    if (e < E) atomicAdd(&cnt[ei[E + e]], 1);
}

__global__ __launch_bounds__(256) void scan_sums(
    const int* __restrict__ cnt, int* __restrict__ tsum, int N) {
    __shared__ int red[256];
    const int t = threadIdx.x;
    const int base = blockIdx.x * 1024;
    int s = 0;
#pragma unroll
    for (int i = 0; i < 4; ++i) {
        int idx = base + t + i * 256;
        s += (idx < N) ? cnt[idx] : 0;
    }
    red[t] = s;
    __syncthreads();
    for (int off = 128; off; off >>= 1) {
        if (t < off) red[t] += red[t + off];
        __syncthreads();
    }
    if (t == 0) tsum[blockIdx.x] = red[0];
}

__global__ __launch_bounds__(1024) void scan_tsum(
    int* __restrict__ tsum, int ntile, int* __restrict__ totalOut) {
    __shared__ int part[1024];
    const int t = threadIdx.x;
    int v = (t < ntile) ? tsum[t] : 0;
    part[t] = v;
    __syncthreads();
    for (int off = 1; off < 1024; off <<= 1) {
        int u = (t >= off) ? part[t - off] : 0;
        __syncthreads();
        part[t] += u;
        __syncthreads();
    }
    if (t < ntile) tsum[t] = part[t] - v;   // exclusive
    if (t == 1023) *totalOut = part[1023];  // row_ptr[N] = E
}

__global__ __launch_bounds__(256) void scan_down(
    const int* __restrict__ cnt, const int* __restrict__ tsumx,
    int* __restrict__ row_ptr, int N) {
    __shared__ int red[256];
    const int t = threadIdx.x;
    const int base = blockIdx.x * 1024 + t * 4;
    int4 v = make_int4(0, 0, 0, 0);
    if (base + 3 < N) {
        v = *(const int4*)(cnt + base);
    } else {
        if (base + 0 < N) v.x = cnt[base + 0];
        if (base + 1 < N) v.y = cnt[base + 1];
        if (base + 2 < N) v.z = cnt[base + 2];
        if (base + 3 < N) v.w = cnt[base + 3];
    }
    int ls = v.x + v.y + v.z + v.w;
    red[t] = ls;
    __syncthreads();
    for (int off = 1; off < 256; off <<= 1) {
        int u = (t >= off) ? red[t - off] : 0;
        __syncthreads();
        red[t] += u;
        __syncthreads();
    }
    int excl = (t == 0 ? 0 : red[t - 1]) + tsumx[blockIdx.x];
    int r0 = excl, r1 = r0 + v.x, r2 = r1 + v.y, r3 = r2 + v.z;
    if (base + 3 < N) {
        *(int4*)(row_ptr + base) = make_int4(r0, r1, r2, r3);
    } else {
        if (base + 0 < N) row_ptr[base + 0] = r0;
        if (base + 1 < N) row_ptr[base + 1] = r1;
        if (base + 2 < N) row_ptr[base + 2] = r2;
        if (base + 3 < N) row_ptr[base + 3] = r3;
    }
}

// single int2 store per edge; pairs[slot] = {eidx, src}
__global__ __launch_bounds__(256) void scatter_kernel(
    const int* __restrict__ ei, const int* __restrict__ row_ptr,
    int* __restrict__ cur, int2* __restrict__ pairs, int E) {
    int e = blockIdx.x * 256 + threadIdx.x;
    if (e < E) {
        int dst = ei[E + e];
        int slot = row_ptr[dst] + atomicAdd(&cur[dst], 1);
        pairs[slot] = make_int2(e, ei[e]);
    }
}

// ---------------------------------------------------------------------------
// K2: pre-transpose weights to bf16 in workspace
// ---------------------------------------------------------------------------
__global__ __launch_bounds__(256) void prep_kernel(
    const void* __restrict__ We, const void* __restrict__ W1,
    const void* __restrict__ W2, u16* __restrict__ WeT,
    u16* __restrict__ W1T, u16* __restrict__ W2T, const int* __restrict__ flag) {
    const bool bf = (*flag != 0);
    const int tid = blockIdx.x * 256 + threadIdx.x;
    const int nthr = gridDim.x * 256;
    for (int i = tid; i < NDIM * EDIM; i += nthr) {
        int k = i >> 7, d = i & 127;
        WeT[d * EDIM + k] = bf ? ((const u16*)We)[i] : f2bf(((const float*)We)[i]);
    }
    for (int i = tid; i < NDIM * NDIM; i += nthr) {
        int k = i >> 7, c = i & 127;
        W1T[c * NDIM + k] = bf ? ((const u16*)W1)[i] : f2bf(((const float*)W1)[i]);
        W2T[c * NDIM + k] = bf ? ((const u16*)W2)[i] : f2bf(((const float*)W2)[i]);
    }
}

// ---------------------------------------------------------------------------
// K3 (v6): CSR aggregation, 32-edge groups (8 x-loads in flight), fused
// h0 = (1+eps)*x[n] + sum(x[src] + relu(attr@We+be)).
// NT only on edge_attr (read-once); pairs lines are reused within the wave.
// ---------------------------------------------------------------------------
__global__ __launch_bounds__(256) void agg_kernel(
    const int* __restrict__ row_ptr, const int2* __restrict__ pairs,
    const void* __restrict__ edge_attr,
    const void* __restrict__ x, const u16* __restrict__ WeT,
    const void* __restrict__ be, const void* __restrict__ eps_p,
    float* __restrict__ h0, int N, const int* __restrict__ flag) {
    const bool bf = (*flag != 0);
    __shared__ float xsumQ[4][4][NDIM];

    const int lane = threadIdx.x & 63;
    const int wid = threadIdx.x >> 6;
    const int q = lane >> 4, l16 = lane & 15;

    const float onepeps = 1.0f + (bf ? bf2f(((const u16*)eps_p)[0])
                                     : ((const float*)eps_p)[0]);

    bf16x8 bfr[8];
#pragma unroll
    for (int nt = 0; nt < 8; ++nt)
        bfr[nt] = *(const bf16x8*)(WeT + (nt * 16 + l16) * EDIM + q * 8);
    f32x4 biasv[8];
#pragma unroll
    for (int nt = 0; nt < 8; ++nt) {
        float bv = bf ? bf2f(((const u16*)be)[nt * 16 + l16])
                      : ((const float*)be)[nt * 16 + l16];
        biasv[nt] = (f32x4){bv, bv, bv, bv};
    }

    const int gwave = blockIdx.x * 4 + wid;
    const int nwaves = gridDim.x * 4;

    for (int n = gwave; n < N; n += nwaves) {
        const int p0 = row_ptr[n], p1 = row_ptr[n + 1];
        float part[8];
#pragma unroll
        for (int nt = 0; nt < 8; ++nt) part[nt] = 0.0f;
        float xa[8];
#pragma unroll
        for (int j = 0; j < 8; ++j) xa[j] = 0.0f;

        for (int base = p0; base < p1; base += 32) {
            const int cnt = min(32, p1 - base);
            // x-gather: quad q handles edges base + q + 4u, u = 0..7
            if (bf) {
#pragma unroll
                for (int u = 0; u < 8; ++u) {
                    int t = q + 4 * u;
                    if (t < cnt) {
                        long pr = *(const long*)(pairs + base + t);
                        int s = (int)(pr >> 32);
                        const u16* xr = (const u16*)x + (long)s * NDIM + l16 * 8;
                        ushort4 a = *(const ushort4*)xr;
                        ushort4 b2 = *(const ushort4*)(xr + 4);
                        xa[0] += bf2f(a.x); xa[1] += bf2f(a.y);
                        xa[2] += bf2f(a.z); xa[3] += bf2f(a.w);
                        xa[4] += bf2f(b2.x); xa[5] += bf2f(b2.y);
                        xa[6] += bf2f(b2.z); xa[7] += bf2f(b2.w);
                    }
                }
            } else {
#pragma unroll
                for (int u = 0; u < 8; ++u) {
                    int t = q + 4 * u;
                    if (t < cnt) {
                        long pr = *(const long*)(pairs + base + t);
                        int s = (int)(pr >> 32);
                        const float* xr = (const float*)x + (long)s * NDIM + l16 * 8;
                        float4 a = *(const float4*)xr;
                        float4 b2 = *(const float4*)(xr + 4);
                        xa[0] += a.x; xa[1] += a.y; xa[2] += a.z; xa[3] += a.w;
                        xa[4] += b2.x; xa[5] += b2.y; xa[6] += b2.z; xa[7] += b2.w;
                    }
                }
            }
            // edge-embed MFMA, first 16 edges of the group
            {
                long pre = *(const long*)(pairs + min(base + l16, p1 - 1));
                int eid = (int)pre;
                bf16x8 af;
                if (bf) {
                    af = __builtin_nontemporal_load(
                        (const bf16x8*)((const u16*)edge_attr + (long)eid * EDIM + q * 8));
                } else {
                    const float* ar = (const float*)edge_attr + (long)eid * EDIM + q * 8;
                    f32x4 a0 = __builtin_nontemporal_load((const f32x4*)ar);
                    f32x4 a1 = __builtin_nontemporal_load((const f32x4*)(ar + 4));
                    af[0] = (short)f2bf(a0[0]); af[1] = (short)f2bf(a0[1]);
                    af[2] = (short)f2bf(a0[2]); af[3] = (short)f2bf(a0[3]);
                    af[4] = (short)f2bf(a1[0]); af[5] = (short)f2bf(a1[1]);
                    af[6] = (short)f2bf(a1[2]); af[7] = (short)f2bf(a1[3]);
                }
#pragma unroll
                for (int nt = 0; nt < 8; ++nt) {
                    f32x4 c = __builtin_amdgcn_mfma_f32_16x16x32_bf16(af, bfr[nt], biasv[nt], 0, 0, 0);
#pragma unroll
                    for (int r = 0; r < 4; ++r)
                        if (q * 4 + r < cnt) part[nt] += fmaxf(c[r], 0.0f);
                }
            }
            // second 16 edges (wave-uniform skip when cnt <= 16)
            if (cnt > 16) {
                long pre = *(const long*)(pairs + min(base + 16 + l16, p1 - 1));
                int eid = (int)pre;
                bf16x8 af;
                if (bf) {
                    af = __builtin_nontemporal_load(
                        (const bf16x8*)((const u16*)edge_attr + (long)eid * EDIM + q * 8));
                } else {
                    const float* ar = (const float*)edge_attr + (long)eid * EDIM + q * 8;
                    f32x4 a0 = __builtin_nontemporal_load((const f32x4*)ar);
                    f32x4 a1 = __builtin_nontemporal_load((const f32x4*)(ar + 4));
                    af[0] = (short)f2bf(a0[0]); af[1] = (short)f2bf(a0[1]);
                    af[2] = (short)f2bf(a0[2]); af[3] = (short)f2bf(a0[3]);
                    af[4] = (short)f2bf(a1[0]); af[5] = (short)f2bf(a1[1]);
                    af[6] = (short)f2bf(a1[2]); af[7] = (short)f2bf(a1[3]);
                }
#pragma unroll
                for (int nt = 0; nt < 8; ++nt) {
                    f32x4 c = __builtin_amdgcn_mfma_f32_16x16x32_bf16(af, bfr[nt], biasv[nt], 0, 0, 0);
#pragma unroll
                    for (int r = 0; r < 4; ++r)
                        if (16 + q * 4 + r < cnt) part[nt] += fmaxf(c[r], 0.0f);
                }
            }
        }
#pragma unroll
        for (int nt = 0; nt < 8; ++nt) {
            part[nt] += __shfl_xor(part[nt], 16);
            part[nt] += __shfl_xor(part[nt], 32);
        }
        *(float4*)&xsumQ[wid][q][l16 * 8 + 0] = make_float4(xa[0], xa[1], xa[2], xa[3]);
        *(float4*)&xsumQ[wid][q][l16 * 8 + 4] = make_float4(xa[4], xa[5], xa[6], xa[7]);
#pragma unroll
        for (int j = 0; j < 2; ++j) {
            int nt = 2 * q + j;
            int d = nt * 16 + l16;
            float xs = xsumQ[wid][0][d] + xsumQ[wid][1][d] +
                       xsumQ[wid][2][d] + xsumQ[wid][3][d];
            float xv = bf ? bf2f(((const u16*)x)[(long)n * NDIM + d])
                          : ((const float*)x)[(long)n * NDIM + d];
            h0[(long)n * NDIM + d] = onepeps * xv + part[nt] + xs;
        }
    }
}

// ---------------------------------------------------------------------------
// split h -> bf16 hi+lo in LDS (fp32-accurate through 2 MFMAs)
// ---------------------------------------------------------------------------
__device__ __forceinline__ void split_store(u16* hHi, u16* hLo, int r, int c, float4 h) {
    ushort4 hi, lo;
    hi.x = f2bf(h.x); lo.x = f2bf(h.x - bf2f(hi.x));
    hi.y = f2bf(h.y); lo.y = f2bf(h.y - bf2f(hi.y));
    hi.z = f2bf(h.z); lo.z = f2bf(h.z - bf2f(hi.z));
    hi.w = f2bf(h.w); lo.w = f2bf(h.w - bf2f(hi.w));
    *(ushort4*)&hHi[r * HSTR + c] = hi;
    *(ushort4*)&hLo[r * HSTR + c] = lo;
}

// ---------------------------------------------------------------------------
// K4: h1 = h0 @ W1 + b1 ; split-atomic col stats. (h0 precomputed by agg)
// ---------------------------------------------------------------------------
__global__ __launch_bounds__(256) void gemm1_kernel(
    const float* __restrict__ h0, const u16* __restrict__ WT,
    const void* __restrict__ b, float* __restrict__ hout,
    float* __restrict__ stats, int M, const int* __restrict__ flag) {
    const bool bf = (*flag != 0);
    __shared__ u16 hHi[64 * HSTR];
    __shared__ u16 hLo[64 * HSTR];
    __shared__ float redS[4][NDIM];
    __shared__ float redQ[4][NDIM];

    const int tid = threadIdx.x;
    const int row0 = blockIdx.x * 64;
    const int cp = (blockIdx.x & (NSPLIT - 1)) * 256;

#pragma unroll
    for (int i = 0; i < 8; ++i) {
        int idx = (tid + i * 256) * 4;
        int r = idx >> 7, c = idx & 127;
        int row = row0 + r;
        float4 h = make_float4(0.f, 0.f, 0.f, 0.f);
        if (row < M) {
            f32x4 hv = __builtin_nontemporal_load((const f32x4*)(h0 + (long)row * NDIM + c));
            h = make_float4(hv[0], hv[1], hv[2], hv[3]);
        }
        split_store(hHi, hLo, r, c, h);
    }
    __syncthreads();

    const int lane = tid & 63, w = tid >> 6;
    const int q = lane >> 4, l16 = lane & 15;

    f32x4 acc[8];
#pragma unroll
    for (int nt = 0; nt < 8; ++nt) {
        float bj = bf ? bf2f(((const u16*)b)[nt * 16 + l16])
                      : ((const float*)b)[nt * 16 + l16];
        acc[nt] = (f32x4){bj, bj, bj, bj};
    }
#pragma unroll
    for (int ks = 0; ks < 4; ++ks) {
        bf16x8 aHi = *(const bf16x8*)&hHi[(w * 16 + l16) * HSTR + ks * 32 + q * 8];
        bf16x8 aLo = *(const bf16x8*)&hLo[(w * 16 + l16) * HSTR + ks * 32 + q * 8];
#pragma unroll
        for (int nt = 0; nt < 8; ++nt) {
            bf16x8 bfr = *(const bf16x8*)(WT + (long)(nt * 16 + l16) * NDIM + ks * 32 + q * 8);
            acc[nt] = __builtin_amdgcn_mfma_f32_16x16x32_bf16(aHi, bfr, acc[nt], 0, 0, 0);
            acc[nt] = __builtin_amdgcn_mfma_f32_16x16x32_bf16(aLo, bfr, acc[nt], 0, 0, 0);
        }
    }

#pragma unroll
    for (int nt = 0; nt < 8; ++nt) {
        float s = 0.f, qs = 0.f;
#pragma unroll
        for (int r = 0; r < 4; ++r) {
            int row = row0 + w * 16 + q * 4 + r;
            if (row < M) {
                float v = acc[nt][r];
                hout[(long)row * NDIM + nt * 16 + l16] = v;
                s += v; qs += v * v;
            }
        }
        s += __shfl_xor(s, 16);  s += __shfl_xor(s, 32);
        qs += __shfl_xor(qs, 16); qs += __shfl_xor(qs, 32);
        if (nt == 2 * q || nt == 2 * q + 1) {
            redS[w][nt * 16 + l16] = s;
            redQ[w][nt * 16 + l16] = qs;
        }
    }
    __syncthreads();
    if (tid < NDIM) {
        atomicAdd(&stats[cp + tid], redS[0][tid] + redS[1][tid] + redS[2][tid] + redS[3][tid]);
    } else {
        int c = tid - NDIM;
        atomicAdd(&stats[cp + NDIM + c], redQ[0][c] + redQ[1][c] + redQ[2][c] + redQ[3][c]);
    }
}

// ---------------------------------------------------------------------------
// K5: a = relu(BN1(h1)) ; h2 = a @ W2 + b2 ; split-atomic col stats.
// ---------------------------------------------------------------------------
__global__ __launch_bounds__(256) void gemm2_kernel(
    const float* __restrict__ h1, const float* __restrict__ statsIn,
    const void* __restrict__ g, const void* __restrict__ beta,
    const u16* __restrict__ WT, const void* __restrict__ b,
    float* __restrict__ hout, float* __restrict__ stats, int M,
    const int* __restrict__ flag) {
    const bool bf = (*flag != 0);
    __shared__ u16 hHi[64 * HSTR];
    __shared__ u16 hLo[64 * HSTR];
    __shared__ float redS[4][NDIM];
    __shared__ float redQ[4][NDIM];
    __shared__ float scaleL[NDIM];
    __shared__ float shiftL[NDIM];

    const int tid = threadIdx.x;
    const int row0 = blockIdx.x * 64;
    const int cp = (blockIdx.x & (NSPLIT - 1)) * 256;

    if (tid < NDIM) {
        float s = 0.f, qv = 0.f;
#pragma unroll 4
        for (int c = 0; c < NSPLIT; ++c) {
            s += statsIn[c * 256 + tid];
            qv += statsIn[c * 256 + NDIM + tid];
        }
        float invM = 1.0f / (float)M;
        float mean = s * invM;
        float var = fmaxf(qv * invM - mean * mean, 0.0f) + 1e-5f;
        float gv = bf ? bf2f(((const u16*)g)[tid]) : ((const float*)g)[tid];
        float bv = bf ? bf2f(((const u16*)beta)[tid]) : ((const float*)beta)[tid];
        float sc = gv * rsqrtf(var);
        scaleL[tid] = sc;
        shiftL[tid] = bv - mean * sc;
    }
    __syncthreads();

#pragma unroll
    for (int i = 0; i < 8; ++i) {
        int idx = (tid + i * 256) * 4;
        int r = idx >> 7, c = idx & 127;
        int row = row0 + r;
        float4 h = make_float4(0.f, 0.f, 0.f, 0.f);
        if (row < M) {
            f32x4 hvv = __builtin_nontemporal_load((const f32x4*)(h1 + (long)row * NDIM + c));
            h.x = fmaxf(hvv[0] * scaleL[c + 0] + shiftL[c + 0], 0.0f);
            h.y = fmaxf(hvv[1] * scaleL[c + 1] + shiftL[c + 1], 0.0f);
            h.z = fmaxf(hvv[2] * scaleL[c + 2] + shiftL[c + 2], 0.0f);
            h.w = fmaxf(hvv[3] * scaleL[c + 3] + shiftL[c + 3], 0.0f);
        }
        split_store(hHi, hLo, r, c, h);
    }
    __syncthreads();

    const int lane = tid & 63, w = tid >> 6;
    const int q = lane >> 4, l16 = lane & 15;

    f32x4 acc[8];
#pragma unroll
    for (int nt = 0; nt < 8; ++nt) {
        float bj = bf ? bf2f(((const u16*)b)[nt * 16 + l16])
                      : ((const float*)b)[nt * 16 + l16];
        acc[nt] = (f32x4){bj, bj, bj, bj};
    }
#pragma unroll
    for (int ks = 0; ks < 4; ++ks) {
        bf16x8 aHi = *(const bf16x8*)&hHi[(w * 16 + l16) * HSTR + ks * 32 + q * 8];
        bf16x8 aLo = *(const bf16x8*)&hLo[(w * 16 + l16) * HSTR + ks * 32 + q * 8];
#pragma unroll
        for (int nt = 0; nt < 8; ++nt) {
            bf16x8 bfr = *(const bf16x8*)(WT + (long)(nt * 16 + l16) * NDIM + ks * 32 + q * 8);
            acc[nt] = __builtin_amdgcn_mfma_f32_16x16x32_bf16(aHi, bfr, acc[nt], 0, 0, 0);
            acc[nt] = __builtin_amdgcn_mfma_f32_16x16x32_bf16(aLo, bfr, acc[nt], 0, 0, 0);
        }
    }

#pragma unroll
    for (int nt = 0; nt < 8; ++nt) {
        float s = 0.f, qs = 0.f;
#pragma unroll
        for (int r = 0; r < 4; ++r) {
            int row = row0 + w * 16 + q * 4 + r;
            if (row < M) {
                float v = acc[nt][r];
                hout[(long)row * NDIM + nt * 16 + l16] = v;
                s += v; qs += v * v;
            }
        }
        s += __shfl_xor(s, 16);  s += __shfl_xor(s, 32);
        qs += __shfl_xor(qs, 16); qs += __shfl_xor(qs, 32);
        if (nt == 2 * q || nt == 2 * q + 1) {
            redS[w][nt * 16 + l16] = s;
            redQ[w][nt * 16 + l16] = qs;
        }
    }
    __syncthreads();
    if (tid < NDIM) {
        atomicAdd(&stats[cp + tid], redS[0][tid] + redS[1][tid] + redS[2][tid] + redS[3][tid]);
    } else {
        int c = tid - NDIM;
        atomicAdd(&stats[cp + NDIM + c], redQ[0][c] + redQ[1][c] + redQ[2][c] + redQ[3][c]);
    }
}

// ---------------------------------------------------------------------------
// K6: out = relu(BN2(h2)) -> output dtype
// ---------------------------------------------------------------------------
__global__ __launch_bounds__(256) void bn2_out_kernel(
    const float* __restrict__ h2, const float* __restrict__ statsIn,
    const void* __restrict__ g, const void* __restrict__ beta,
    void* __restrict__ out, int M, const int* __restrict__ flag) {
    const bool bf = (*flag != 0);
    __shared__ float scaleL[NDIM];
    __shared__ float shiftL[NDIM];
    const int tid = threadIdx.x;
    if (tid < NDIM) {
        float s = 0.f, qv = 0.f;
#pragma unroll 4
        for (int c = 0; c < NSPLIT; ++c) {
            s += statsIn[c * 256 + tid];
            qv += statsIn[c * 256 + NDIM + tid];
        }
        float invM = 1.0f / (float)M;
        float mean = s * invM;
        float var = fmaxf(qv * invM - mean * mean, 0.0f) + 1e-5f;
        float gv = bf ? bf2f(((const u16*)g)[tid]) : ((const float*)g)[tid];
        float bv = bf ? bf2f(((const u16*)beta)[tid]) : ((const float*)beta)[tid];
        float sc = gv * rsqrtf(var);
        scaleL[tid] = sc;
        shiftL[tid] = bv - mean * sc;
    }
    __syncthreads();

    const int n4 = M * NDIM / 4;
    for (int i = blockIdx.x * 256 + tid; i < n4; i += gridDim.x * 256) {
        int c = (i & 31) * 4;
        f32x4 hv = __builtin_nontemporal_load((const f32x4*)(h2 + (long)i * 4));
        float o0 = fmaxf(hv[0] * scaleL[c + 0] + shiftL[c + 0], 0.0f);
        float o1 = fmaxf(hv[1] * scaleL[c + 1] + shiftL[c + 1], 0.0f);
        float o2 = fmaxf(hv[2] * scaleL[c + 2] + shiftL[c + 2], 0.0f);
        float o3 = fmaxf(hv[3] * scaleL[c + 3] + shiftL[c + 3], 0.0f);
        if (bf) {
            u16x4 o;
            o.x = f2bf(o0); o.y = f2bf(o1); o.z = f2bf(o2); o.w = f2bf(o3);
            __builtin_nontemporal_store(o, (u16x4*)((u16*)out + (long)i * 4));
        } else {
            f32x4 o = (f32x4){o0, o1, o2, o3};
            __builtin_nontemporal_store(o, (f32x4*)((float*)out + (long)i * 4));
        }
    }
}

extern "C" void kernel_launch(void* const* d_in, const int* in_sizes, int n_in,
                              void* d_out, int out_size, void* d_ws, size_t ws_size,
                              hipStream_t stream) {
    const void* x         = d_in[0];
    const int*  ei        = (const int*)d_in[1];
    const void* edge_attr = d_in[2];
    const void* eps_p     = d_in[3];
    const void* We        = d_in[4];
    const void* be        = d_in[5];
    const void* W1        = d_in[6];
    const void* b1        = d_in[7];
    const void* g1        = d_in[8];
    const void* beta1     = d_in[9];
    const void* W2        = d_in[10];
    const void* b2        = d_in[11];
    const void* g2        = d_in[12];
    const void* beta2     = d_in[13];

    int N = in_sizes[0] / NDIM;                // 50000
    int E = in_sizes[1] / 2;                   // 800000
    const size_t nd = (size_t)N * NDIM;

    float* h0     = (float*)d_ws;              // [nd]; reused as h2
    float* h1     = h0 + nd;                   // [nd]
    float* stats1 = h1 + nd;                   // [NSPLIT*256]
    float* stats2 = stats1 + NSPLIT * 256;     // [NSPLIT*256]
    int*   flag   = (int*)(stats2 + NSPLIT * 256); // [4]
    u16*   WeT    = (u16*)(flag + 4);          // [128*32]
    u16*   W1T    = WeT + NDIM * EDIM;         // [128*128]
    u16*   W2T    = W1T + NDIM * NDIM;         // [128*128]
    int*   tsum   = (int*)(W2T + NDIM * NDIM); // [1024]
    float* h2     = h0;                        // reuse

    // CSR scratch overlaid on h1 (dead before gemm1 writes h1)
    int2* pairs   = (int2*)h1;                 // [E]
    int* cnt      = (int*)(pairs + E);         // [N]
    int* cur      = cnt + N;                   // [N]
    int* row_ptr  = cur + N;                   // [N+1]

    detect_kernel<<<1, 64, 0, stream>>>(x, flag);
    hipMemsetAsync(stats1, 0, 2 * NSPLIT * 256 * sizeof(float), stream);
    hipMemsetAsync(cnt, 0, 2 * (size_t)N * sizeof(int), stream);

    const int eblk = (E + 255) / 256;
    const int ntile = (N + 1023) / 1024;
    hist_kernel<<<eblk, 256, 0, stream>>>(ei, cnt, E);
    scan_sums<<<ntile, 256, 0, stream>>>(cnt, tsum, N);
    scan_tsum<<<1, 1024, 0, stream>>>(tsum, ntile, &row_ptr[N]);
    scan_down<<<ntile, 256, 0, stream>>>(cnt, tsum, row_ptr, N);
    scatter_kernel<<<eblk, 256, 0, stream>>>(ei, row_ptr, cur, pairs, E);

    prep_kernel<<<64, 256, 0, stream>>>(We, W1, W2, WeT, W1T, W2T, flag);

    agg_kernel<<<2048, 256, 0, stream>>>(row_ptr, pairs, edge_attr, x,
                                         WeT, be, eps_p, h0, N, flag);

    const int nblk = (N + 63) / 64;
    gemm1_kernel<<<nblk, 256, 0, stream>>>(h0, W1T, b1, h1, stats1, N, flag);
    gemm2_kernel<<<nblk, 256, 0, stream>>>(h1, stats1, g1, beta1, W2T, b2, h2, stats2, N, flag);
    bn2_out_kernel<<<2048, 256, 0, stream>>>(h2, stats2, g2, beta2, d_out, N, flag);
}

// Round 8
// 465.498 us; speedup vs baseline: 1.0370x; 1.0370x over previous
//
#include <hip/hip_runtime.h>
#include <hip/hip_bf16.h>

typedef unsigned short u16;
typedef __attribute__((ext_vector_type(8))) short bf16x8;
typedef __attribute__((ext_vector_type(4))) float f32x4;
typedef __attribute__((ext_vector_type(4))) unsigned short u16x4;

#define NDIM 128
#define EDIM 32
#define HSTR 136     // gemm h LDS stride (u16): 16B aligned, 2-way banks (free)
#define NSPLIT 32    // stats atomic split copies

__device__ __forceinline__ float bf2f(u16 u) {
    union { unsigned int i; float f; } v; v.i = ((unsigned int)u) << 16; return v.f;
}
__device__ __forceinline__ u16 f2bf(float f) {
    __hip_bfloat16 h = __float2bfloat16(f);
    return *reinterpret_cast<u16*>(&h);
}

// ---------------------------------------------------------------------------
// K0: dtype detector (flag: 1 = bf16, 0 = fp32)
// ---------------------------------------------------------------------------
__global__ void detect_kernel(const void* __restrict__ x, int* __restrict__ flag) {
    __shared__ int cnt;
    if (threadIdx.x == 0) cnt = 0;
    __syncthreads();
    const u16* p = (const u16*)x;
    int crazy = 0;
    for (int i = threadIdx.x; i < 512; i += 64) {
        u16 v = p[2 * i];
        int e = (v >> 7) & 0xFF;
        if (e != 0 && (e < 100 || e > 150)) crazy++;
    }
    atomicAdd(&cnt, crazy);
    __syncthreads();
    if (threadIdx.x == 0) *flag = (cnt > 128) ? 0 : 1;
}

// ---------------------------------------------------------------------------
// CSR build: histogram -> coalesced 3-phase scan -> scatter
// ---------------------------------------------------------------------------
__global__ __launch_bounds__(256) void hist_kernel(
    const int* __restrict__ ei, int* __restrict__ cnt, int E) {
    int e = blockIdx.x * 256 + threadIdx.x;
    if (e < E) atomicAdd(&cnt[ei[E + e]], 1);
}

__global__ __launch_bounds__(256) void scan_sums(
    const int* __restrict__ cnt, int* __restrict__ tsum, int N) {
    __shared__ int red[256];
    const int t = threadIdx.x;
    const int base = blockIdx.x * 1024;
    int s = 0;
#pragma unroll
    for (int i = 0; i < 4; ++i) {
        int idx = base + t + i * 256;
        s += (idx < N) ? cnt[idx] : 0;
    }
    red[t] = s;
    __syncthreads();
    for (int off = 128; off; off >>= 1) {
        if (t < off) red[t] += red[t + off];
        __syncthreads();
    }
    if (t == 0) tsum[blockIdx.x] = red[0];
}

__global__ __launch_bounds__(1024) void scan_tsum(
    int* __restrict__ tsum, int ntile, int* __restrict__ totalOut) {
    __shared__ int part[1024];
    const int t = threadIdx.x;
    int v = (t < ntile) ? tsum[t] : 0;
    part[t] = v;
    __syncthreads();
    for (int off = 1; off < 1024; off <<= 1) {
        int u = (t >= off) ? part[t - off] : 0;
        __syncthreads();
        part[t] += u;
        __syncthreads();
    }
    if (t < ntile) tsum[t] = part[t] - v;   // exclusive
    if (t == 1023) *totalOut = part[1023];  // row_ptr[N] = E
}

__global__ __launch_bounds__(256) void scan_down(
    const int* __restrict__ cnt, const int* __restrict__ tsumx,
    int* __restrict__ row_ptr, int N) {
    __shared__ int red[256];
    const int t = threadIdx.x;
    const int base = blockIdx.x * 1024 + t * 4;
    int4 v = make_int4(0, 0, 0, 0);
    if (base + 3 < N) {
        v = *(const int4*)(cnt + base);
    } else {
        if (base + 0 < N) v.x = cnt[base + 0];
        if (base + 1 < N) v.y = cnt[base + 1];
        if (base + 2 < N) v.z = cnt[base + 2];
        if (base + 3 < N) v.w = cnt[base + 3];
    }
    int ls = v.x + v.y + v.z + v.w;
    red[t] = ls;
    __syncthreads();
    for (int off = 1; off < 256; off <<= 1) {
        int u = (t >= off) ? red[t - off] : 0;
        __syncthreads();
        red[t] += u;
        __syncthreads();
    }
    int excl = (t == 0 ? 0 : red[t - 1]) + tsumx[blockIdx.x];
    int r0 = excl, r1 = r0 + v.x, r2 = r1 + v.y, r3 = r2 + v.z;
    if (base + 3 < N) {
        *(int4*)(row_ptr + base) = make_int4(r0, r1, r2, r3);
    } else {
        if (base + 0 < N) row_ptr[base + 0] = r0;
        if (base + 1 < N) row_ptr[base + 1] = r1;
        if (base + 2 < N) row_ptr[base + 2] = r2;
        if (base + 3 < N) row_ptr[base + 3] = r3;
    }
}

// single int2 store per edge; pairs[slot] = {eidx, src}
__global__ __launch_bounds__(256) void scatter_kernel(
    const int* __restrict__ ei, const int* __restrict__ row_ptr,
    int* __restrict__ cur, int2* __restrict__ pairs, int E) {
    int e = blockIdx.x * 256 + threadIdx.x;
    if (e < E) {
        int dst = ei[E + e];
        int slot = row_ptr[dst] + atomicAdd(&cur[dst], 1);
        pairs[slot] = make_int2(e, ei[e]);
    }
}

// ---------------------------------------------------------------------------
// K2: pre-transpose weights to bf16 in workspace
// ---------------------------------------------------------------------------
__global__ __launch_bounds__(256) void prep_kernel(
    const void* __restrict__ We, const void* __restrict__ W1,
    const void* __restrict__ W2, u16* __restrict__ WeT,
    u16* __restrict__ W1T, u16* __restrict__ W2T, const int* __restrict__ flag) {
    const bool bf = (*flag != 0);
    const int tid = blockIdx.x * 256 + threadIdx.x;
    const int nthr = gridDim.x * 256;
    for (int i = tid; i < NDIM * EDIM; i += nthr) {
        int k = i >> 7, d = i & 127;
        WeT[d * EDIM + k] = bf ? ((const u16*)We)[i] : f2bf(((const float*)We)[i]);
    }
    for (int i = tid; i < NDIM * NDIM; i += nthr) {
        int k = i >> 7, c = i & 127;
        W1T[c * NDIM + k] = bf ? ((const u16*)W1)[i] : f2bf(((const float*)W1)[i]);
        W2T[c * NDIM + k] = bf ? ((const u16*)W2)[i] : f2bf(((const float*)W2)[i]);
    }
}

// ---------------------------------------------------------------------------
// K3 (v7): round-5 gather structure (16-edge groups, 4 predicated slots,
// VGPR~60 -> 8 waves/SIMD) + fused h0 epilogue from v6.
// v6's 32-edge groups regressed (VGPR 68 -> load serialization): reverted.
// ---------------------------------------------------------------------------
__global__ __launch_bounds__(256) void agg_kernel(
    const int* __restrict__ row_ptr, const int2* __restrict__ pairs,
    const void* __restrict__ edge_attr,
    const void* __restrict__ x, const u16* __restrict__ WeT,
    const void* __restrict__ be, const void* __restrict__ eps_p,
    float* __restrict__ h0, int N, const int* __restrict__ flag) {
    const bool bf = (*flag != 0);
    __shared__ float xsumQ[4][4][NDIM];

    const int lane = threadIdx.x & 63;
    const int wid = threadIdx.x >> 6;
    const int q = lane >> 4, l16 = lane & 15;

    const float onepeps = 1.0f + (bf ? bf2f(((const u16*)eps_p)[0])
                                     : ((const float*)eps_p)[0]);

    bf16x8 bfr[8];
#pragma unroll
    for (int nt = 0; nt < 8; ++nt)
        bfr[nt] = *(const bf16x8*)(WeT + (nt * 16 + l16) * EDIM + q * 8);
    f32x4 biasv[8];
#pragma unroll
    for (int nt = 0; nt < 8; ++nt) {
        float bv = bf ? bf2f(((const u16*)be)[nt * 16 + l16])
                      : ((const float*)be)[nt * 16 + l16];
        biasv[nt] = (f32x4){bv, bv, bv, bv};
    }

    const int gwave = blockIdx.x * 4 + wid;
    const int nwaves = gridDim.x * 4;

    for (int n = gwave; n < N; n += nwaves) {
        const int p0 = row_ptr[n], p1 = row_ptr[n + 1];
        float part[8];
#pragma unroll
        for (int nt = 0; nt < 8; ++nt) part[nt] = 0.0f;
        float xa[8];
#pragma unroll
        for (int j = 0; j < 8; ++j) xa[j] = 0.0f;

        for (int base = p0; base < p1; base += 16) {
            const int cnt = min(16, p1 - base);
            // x-gather: quad q handles edges base+q, +4, +8, +12
            if (bf) {
#pragma unroll
                for (int u = 0; u < 4; ++u) {
                    int t = q + 4 * u;
                    if (t < cnt) {
                        long pr = __builtin_nontemporal_load((const long*)(pairs + base + t));
                        int s = (int)(pr >> 32);
                        const u16* xr = (const u16*)x + (long)s * NDIM + l16 * 8;
                        ushort4 a = *(const ushort4*)xr;
                        ushort4 b2 = *(const ushort4*)(xr + 4);
                        xa[0] += bf2f(a.x); xa[1] += bf2f(a.y);
                        xa[2] += bf2f(a.z); xa[3] += bf2f(a.w);
                        xa[4] += bf2f(b2.x); xa[5] += bf2f(b2.y);
                        xa[6] += bf2f(b2.z); xa[7] += bf2f(b2.w);
                    }
                }
            } else {
#pragma unroll
                for (int u = 0; u < 4; ++u) {
                    int t = q + 4 * u;
                    if (t < cnt) {
                        long pr = __builtin_nontemporal_load((const long*)(pairs + base + t));
                        int s = (int)(pr >> 32);
                        const float* xr = (const float*)x + (long)s * NDIM + l16 * 8;
                        float4 a = *(const float4*)xr;
                        float4 b2 = *(const float4*)(xr + 4);
                        xa[0] += a.x; xa[1] += a.y; xa[2] += a.z; xa[3] += a.w;
                        xa[4] += b2.x; xa[5] += b2.y; xa[6] += b2.z; xa[7] += b2.w;
                    }
                }
            }
            // A-frag: attr row of edge base+l16
            long pre = __builtin_nontemporal_load(
                (const long*)(pairs + min(base + l16, p1 - 1)));
            int eid = (int)pre;
            bf16x8 af;
            if (bf) {
                af = __builtin_nontemporal_load(
                    (const bf16x8*)((const u16*)edge_attr + (long)eid * EDIM + q * 8));
            } else {
                const float* ar = (const float*)edge_attr + (long)eid * EDIM + q * 8;
                f32x4 a0 = __builtin_nontemporal_load((const f32x4*)ar);
                f32x4 a1 = __builtin_nontemporal_load((const f32x4*)(ar + 4));
                af[0] = (short)f2bf(a0[0]); af[1] = (short)f2bf(a0[1]);
                af[2] = (short)f2bf(a0[2]); af[3] = (short)f2bf(a0[3]);
                af[4] = (short)f2bf(a1[0]); af[5] = (short)f2bf(a1[1]);
                af[6] = (short)f2bf(a1[2]); af[7] = (short)f2bf(a1[3]);
            }
#pragma unroll
            for (int nt = 0; nt < 8; ++nt) {
                f32x4 c = __builtin_amdgcn_mfma_f32_16x16x32_bf16(af, bfr[nt], biasv[nt], 0, 0, 0);
#pragma unroll
                for (int r = 0; r < 4; ++r)
                    if (q * 4 + r < cnt) part[nt] += fmaxf(c[r], 0.0f);
            }
        }
        // cross-quad reduce of MFMA parts
#pragma unroll
        for (int nt = 0; nt < 8; ++nt) {
            part[nt] += __shfl_xor(part[nt], 16);
            part[nt] += __shfl_xor(part[nt], 32);
        }
        // exchange x partials through LDS (per-wave slice, wave-coherent)
        *(float4*)&xsumQ[wid][q][l16 * 8 + 0] = make_float4(xa[0], xa[1], xa[2], xa[3]);
        *(float4*)&xsumQ[wid][q][l16 * 8 + 4] = make_float4(xa[4], xa[5], xa[6], xa[7]);
#pragma unroll
        for (int j = 0; j < 2; ++j) {
            int nt = 2 * q + j;
            int d = nt * 16 + l16;
            float xs = xsumQ[wid][0][d] + xsumQ[wid][1][d] +
                       xsumQ[wid][2][d] + xsumQ[wid][3][d];
            float xv = bf ? bf2f(((const u16*)x)[(long)n * NDIM + d])
                          : ((const float*)x)[(long)n * NDIM + d];
            h0[(long)n * NDIM + d] = onepeps * xv + part[nt] + xs;
        }
    }
}

// ---------------------------------------------------------------------------
// split h -> bf16 hi+lo in LDS (fp32-accurate through 2 MFMAs)
// ---------------------------------------------------------------------------
__device__ __forceinline__ void split_store(u16* hHi, u16* hLo, int r, int c, float4 h) {
    ushort4 hi, lo;
    hi.x = f2bf(h.x); lo.x = f2bf(h.x - bf2f(hi.x));
    hi.y = f2bf(h.y); lo.y = f2bf(h.y - bf2f(hi.y));
    hi.z = f2bf(h.z); lo.z = f2bf(h.z - bf2f(hi.z));
    hi.w = f2bf(h.w); lo.w = f2bf(h.w - bf2f(hi.w));
    *(ushort4*)&hHi[r * HSTR + c] = hi;
    *(ushort4*)&hLo[r * HSTR + c] = lo;
}

// ---------------------------------------------------------------------------
// K4: h1 = h0 @ W1 + b1 ; split-atomic col stats. (h0 precomputed by agg)
// ---------------------------------------------------------------------------
__global__ __launch_bounds__(256) void gemm1_kernel(
    const float* __restrict__ h0, const u16* __restrict__ WT,
    const void* __restrict__ b, float* __restrict__ hout,
    float* __restrict__ stats, int M, const int* __restrict__ flag) {
    const bool bf = (*flag != 0);
    __shared__ u16 hHi[64 * HSTR];
    __shared__ u16 hLo[64 * HSTR];
    __shared__ float redS[4][NDIM];
    __shared__ float redQ[4][NDIM];

    const int tid = threadIdx.x;
    const int row0 = blockIdx.x * 64;
    const int cp = (blockIdx.x & (NSPLIT - 1)) * 256;

#pragma unroll
    for (int i = 0; i < 8; ++i) {
        int idx = (tid + i * 256) * 4;
        int r = idx >> 7, c = idx & 127;
        int row = row0 + r;
        float4 h = make_float4(0.f, 0.f, 0.f, 0.f);
        if (row < M) {
            f32x4 hv = __builtin_nontemporal_load((const f32x4*)(h0 + (long)row * NDIM + c));
            h = make_float4(hv[0], hv[1], hv[2], hv[3]);
        }
        split_store(hHi, hLo, r, c, h);
    }
    __syncthreads();

    const int lane = tid & 63, w = tid >> 6;
    const int q = lane >> 4, l16 = lane & 15;

    f32x4 acc[8];
#pragma unroll
    for (int nt = 0; nt < 8; ++nt) {
        float bj = bf ? bf2f(((const u16*)b)[nt * 16 + l16])
                      : ((const float*)b)[nt * 16 + l16];
        acc[nt] = (f32x4){bj, bj, bj, bj};
    }
#pragma unroll
    for (int ks = 0; ks < 4; ++ks) {
        bf16x8 aHi = *(const bf16x8*)&hHi[(w * 16 + l16) * HSTR + ks * 32 + q * 8];
        bf16x8 aLo = *(const bf16x8*)&hLo[(w * 16 + l16) * HSTR + ks * 32 + q * 8];
#pragma unroll
        for (int nt = 0; nt < 8; ++nt) {
            bf16x8 bfr = *(const bf16x8*)(WT + (long)(nt * 16 + l16) * NDIM + ks * 32 + q * 8);
            acc[nt] = __builtin_amdgcn_mfma_f32_16x16x32_bf16(aHi, bfr, acc[nt], 0, 0, 0);
            acc[nt] = __builtin_amdgcn_mfma_f32_16x16x32_bf16(aLo, bfr, acc[nt], 0, 0, 0);
        }
    }

#pragma unroll
    for (int nt = 0; nt < 8; ++nt) {
        float s = 0.f, qs = 0.f;
#pragma unroll
        for (int r = 0; r < 4; ++r) {
            int row = row0 + w * 16 + q * 4 + r;
            if (row < M) {
                float v = acc[nt][r];
                hout[(long)row * NDIM + nt * 16 + l16] = v;
                s += v; qs += v * v;
            }
        }
        s += __shfl_xor(s, 16);  s += __shfl_xor(s, 32);
        qs += __shfl_xor(qs, 16); qs += __shfl_xor(qs, 32);
        if (nt == 2 * q || nt == 2 * q + 1) {
            redS[w][nt * 16 + l16] = s;
            redQ[w][nt * 16 + l16] = qs;
        }
    }
    __syncthreads();
    if (tid < NDIM) {
        atomicAdd(&stats[cp + tid], redS[0][tid] + redS[1][tid] + redS[2][tid] + redS[3][tid]);
    } else {
        int c = tid - NDIM;
        atomicAdd(&stats[cp + NDIM + c], redQ[0][c] + redQ[1][c] + redQ[2][c] + redQ[3][c]);
    }
}

// ---------------------------------------------------------------------------
// K5: a = relu(BN1(h1)) ; h2 = a @ W2 + b2 ; split-atomic col stats.
// ---------------------------------------------------------------------------
__global__ __launch_bounds__(256) void gemm2_kernel(
    const float* __restrict__ h1, const float* __restrict__ statsIn,
    const void* __restrict__ g, const void* __restrict__ beta,
    const u16* __restrict__ WT, const void* __restrict__ b,
    float* __restrict__ hout, float* __restrict__ stats, int M,
    const int* __restrict__ flag) {
    const bool bf = (*flag != 0);
    __shared__ u16 hHi[64 * HSTR];
    __shared__ u16 hLo[64 * HSTR];
    __shared__ float redS[4][NDIM];
    __shared__ float redQ[4][NDIM];
    __shared__ float scaleL[NDIM];
    __shared__ float shiftL[NDIM];

    const int tid = threadIdx.x;
    const int row0 = blockIdx.x * 64;
    const int cp = (blockIdx.x & (NSPLIT - 1)) * 256;

    if (tid < NDIM) {
        float s = 0.f, qv = 0.f;
#pragma unroll 4
        for (int c = 0; c < NSPLIT; ++c) {
            s += statsIn[c * 256 + tid];
            qv += statsIn[c * 256 + NDIM + tid];
        }
        float invM = 1.0f / (float)M;
        float mean = s * invM;
        float var = fmaxf(qv * invM - mean * mean, 0.0f) + 1e-5f;
        float gv = bf ? bf2f(((const u16*)g)[tid]) : ((const float*)g)[tid];
        float bv = bf ? bf2f(((const u16*)beta)[tid]) : ((const float*)beta)[tid];
        float sc = gv * rsqrtf(var);
        scaleL[tid] = sc;
        shiftL[tid] = bv - mean * sc;
    }
    __syncthreads();

#pragma unroll
    for (int i = 0; i < 8; ++i) {
        int idx = (tid + i * 256) * 4;
        int r = idx >> 7, c = idx & 127;
        int row = row0 + r;
        float4 h = make_float4(0.f, 0.f, 0.f, 0.f);
        if (row < M) {
            f32x4 hvv = __builtin_nontemporal_load((const f32x4*)(h1 + (long)row * NDIM + c));
            h.x = fmaxf(hvv[0] * scaleL[c + 0] + shiftL[c + 0], 0.0f);
            h.y = fmaxf(hvv[1] * scaleL[c + 1] + shiftL[c + 1], 0.0f);
            h.z = fmaxf(hvv[2] * scaleL[c + 2] + shiftL[c + 2], 0.0f);
            h.w = fmaxf(hvv[3] * scaleL[c + 3] + shiftL[c + 3], 0.0f);
        }
        split_store(hHi, hLo, r, c, h);
    }
    __syncthreads();

    const int lane = tid & 63, w = tid >> 6;
    const int q = lane >> 4, l16 = lane & 15;

    f32x4 acc[8];
#pragma unroll
    for (int nt = 0; nt < 8; ++nt) {
        float bj = bf ? bf2f(((const u16*)b)[nt * 16 + l16])
                      : ((const float*)b)[nt * 16 + l16];
        acc[nt] = (f32x4){bj, bj, bj, bj};
    }
#pragma unroll
    for (int ks = 0; ks < 4; ++ks) {
        bf16x8 aHi = *(const bf16x8*)&hHi[(w * 16 + l16) * HSTR + ks * 32 + q * 8];
        bf16x8 aLo = *(const bf16x8*)&hLo[(w * 16 + l16) * HSTR + ks * 32 + q * 8];
#pragma unroll
        for (int nt = 0; nt < 8; ++nt) {
            bf16x8 bfr = *(const bf16x8*)(WT + (long)(nt * 16 + l16) * NDIM + ks * 32 + q * 8);
            acc[nt] = __builtin_amdgcn_mfma_f32_16x16x32_bf16(aHi, bfr, acc[nt], 0, 0, 0);
            acc[nt] = __builtin_amdgcn_mfma_f32_16x16x32_bf16(aLo, bfr, acc[nt], 0, 0, 0);
        }
    }

#pragma unroll
    for (int nt = 0; nt < 8; ++nt) {
        float s = 0.f, qs = 0.f;
#pragma unroll
        for (int r = 0; r < 4; ++r) {
            int row = row0 + w * 16 + q * 4 + r;
            if (row < M) {
                float v = acc[nt][r];
                hout[(long)row * NDIM + nt * 16 + l16] = v;
                s += v; qs += v * v;
            }
        }
        s += __shfl_xor(s, 16);  s += __shfl_xor(s, 32);
        qs += __shfl_xor(qs, 16); qs += __shfl_xor(qs, 32);
        if (nt == 2 * q || nt == 2 * q + 1) {
            redS[w][nt * 16 + l16] = s;
            redQ[w][nt * 16 + l16] = qs;
        }
    }
    __syncthreads();
    if (tid < NDIM) {
        atomicAdd(&stats[cp + tid], redS[0][tid] + redS[1][tid] + redS[2][tid] + redS[3][tid]);
    } else {
        int c = tid - NDIM;
        atomicAdd(&stats[cp + NDIM + c], redQ[0][c] + redQ[1][c] + redQ[2][c] + redQ[3][c]);
    }
}

// ---------------------------------------------------------------------------
// K6: out = relu(BN2(h2)) -> output dtype
// ---------------------------------------------------------------------------
__global__ __launch_bounds__(256) void bn2_out_kernel(
    const float* __restrict__ h2, const float* __restrict__ statsIn,
    const void* __restrict__ g, const void* __restrict__ beta,
    void* __restrict__ out, int M, const int* __restrict__ flag) {
    const bool bf = (*flag != 0);
    __shared__ float scaleL[NDIM];
    __shared__ float shiftL[NDIM];
    const int tid = threadIdx.x;
    if (tid < NDIM) {
        float s = 0.f, qv = 0.f;
#pragma unroll 4
        for (int c = 0; c < NSPLIT; ++c) {
            s += statsIn[c * 256 + tid];
            qv += statsIn[c * 256 + NDIM + tid];
        }
        float invM = 1.0f / (float)M;
        float mean = s * invM;
        float var = fmaxf(qv * invM - mean * mean, 0.0f) + 1e-5f;
        float gv = bf ? bf2f(((const u16*)g)[tid]) : ((const float*)g)[tid];
        float bv = bf ? bf2f(((const u16*)beta)[tid]) : ((const float*)beta)[tid];
        float sc = gv * rsqrtf(var);
        scaleL[tid] = sc;
        shiftL[tid] = bv - mean * sc;
    }
    __syncthreads();

    const int n4 = M * NDIM / 4;
    for (int i = blockIdx.x * 256 + tid; i < n4; i += gridDim.x * 256) {
        int c = (i & 31) * 4;
        f32x4 hv = __builtin_nontemporal_load((const f32x4*)(h2 + (long)i * 4));
        float o0 = fmaxf(hv[0] * scaleL[c + 0] + shiftL[c + 0], 0.0f);
        float o1 = fmaxf(hv[1] * scaleL[c + 1] + shiftL[c + 1], 0.0f);
        float o2 = fmaxf(hv[2] * scaleL[c + 2] + shiftL[c + 2], 0.0f);
        float o3 = fmaxf(hv[3] * scaleL[c + 3] + shiftL[c + 3], 0.0f);
        if (bf) {
            u16x4 o;
            o.x = f2bf(o0); o.y = f2bf(o1); o.z = f2bf(o2); o.w = f2bf(o3);
            __builtin_nontemporal_store(o, (u16x4*)((u16*)out + (long)i * 4));
        } else {
            f32x4 o = (f32x4){o0, o1, o2, o3};
            __builtin_nontemporal_store(o, (f32x4*)((float*)out + (long)i * 4));
        }
    }
}

extern "C" void kernel_launch(void* const* d_in, const int* in_sizes, int n_in,
                              void* d_out, int out_size, void* d_ws, size_t ws_size,
                              hipStream_t stream) {
    const void* x         = d_in[0];
    const int*  ei        = (const int*)d_in[1];
    const void* edge_attr = d_in[2];
    const void* eps_p     = d_in[3];
    const void* We        = d_in[4];
    const void* be        = d_in[5];
    const void* W1        = d_in[6];
    const void* b1        = d_in[7];
    const void* g1        = d_in[8];
    const void* beta1     = d_in[9];
    const void* W2        = d_in[10];
    const void* b2        = d_in[11];
    const void* g2        = d_in[12];
    const void* beta2     = d_in[13];

    int N = in_sizes[0] / NDIM;                // 50000
    int E = in_sizes[1] / 2;                   // 800000
    const size_t nd = (size_t)N * NDIM;

    float* h0     = (float*)d_ws;              // [nd]; reused as h2
    float* h1     = h0 + nd;                   // [nd]
    float* stats1 = h1 + nd;                   // [NSPLIT*256]
    float* stats2 = stats1 + NSPLIT * 256;     // [NSPLIT*256]
    int*   flag   = (int*)(stats2 + NSPLIT * 256); // [4]
    u16*   WeT    = (u16*)(flag + 4);          // [128*32]
    u16*   W1T    = WeT + NDIM * EDIM;         // [128*128]
    u16*   W2T    = W1T + NDIM * NDIM;         // [128*128]
    int*   tsum   = (int*)(W2T + NDIM * NDIM); // [1024]
    float* h2     = h0;                        // reuse

    // CSR scratch overlaid on h1 (dead before gemm1 writes h1)
    int2* pairs   = (int2*)h1;                 // [E]
    int* cnt      = (int*)(pairs + E);         // [N]
    int* cur      = cnt + N;                   // [N]
    int* row_ptr  = cur + N;                   // [N+1]

    detect_kernel<<<1, 64, 0, stream>>>(x, flag);
    hipMemsetAsync(stats1, 0, 2 * NSPLIT * 256 * sizeof(float), stream);
    hipMemsetAsync(cnt, 0, 2 * (size_t)N * sizeof(int), stream);

    const int eblk = (E + 255) / 256;
    const int ntile = (N + 1023) / 1024;
    hist_kernel<<<eblk, 256, 0, stream>>>(ei, cnt, E);
    scan_sums<<<ntile, 256, 0, stream>>>(cnt, tsum, N);
    scan_tsum<<<1, 1024, 0, stream>>>(tsum, ntile, &row_ptr[N]);
    scan_down<<<ntile, 256, 0, stream>>>(cnt, tsum, row_ptr, N);
    scatter_kernel<<<eblk, 256, 0, stream>>>(ei, row_ptr, cur, pairs, E);

    prep_kernel<<<64, 256, 0, stream>>>(We, W1, W2, WeT, W1T, W2T, flag);

    // 4096 blocks: 16 queued/CU over ~8 resident -> smooths tail imbalance
    agg_kernel<<<4096, 256, 0, stream>>>(row_ptr, pairs, edge_attr, x,
                                         WeT, be, eps_p, h0, N, flag);

    const int nblk = (N + 63) / 64;
    gemm1_kernel<<<nblk, 256, 0, stream>>>(h0, W1T, b1, h1, stats1, N, flag);
    gemm2_kernel<<<nblk, 256, 0, stream>>>(h1, stats1, g1, beta1, W2T, b2, h2, stats2, N, flag);
    bn2_out_kernel<<<2048, 256, 0, stream>>>(h2, stats2, g2, beta2, d_out, N, flag);
}

// Round 9
// 432.006 us; speedup vs baseline: 1.1174x; 1.0775x over previous
//
#include <hip/hip_runtime.h>
#include <hip/hip_bf16.h>

typedef unsigned short u16;
typedef __attribute__((ext_vector_type(8))) short bf16x8;
typedef __attribute__((ext_vector_type(4))) float f32x4;
typedef __attribute__((ext_vector_type(4))) unsigned short u16x4;

#define NDIM 128
#define EDIM 32
#define HSTR 136     // gemm h LDS stride (u16): 16B aligned, 2-way banks (free)
#define NSPLIT 32    // stats atomic split copies

__device__ __forceinline__ float bf2f(u16 u) {
    union { unsigned int i; float f; } v; v.i = ((unsigned int)u) << 16; return v.f;
}
__device__ __forceinline__ u16 f2bf(float f) {
    __hip_bfloat16 h = __float2bfloat16(f);
    return *reinterpret_cast<u16*>(&h);
}

// ---------------------------------------------------------------------------
// K0: dtype detector (flag: 1 = bf16, 0 = fp32)
// ---------------------------------------------------------------------------
__global__ void detect_kernel(const void* __restrict__ x, int* __restrict__ flag) {
    __shared__ int cnt;
    if (threadIdx.x == 0) cnt = 0;
    __syncthreads();
    const u16* p = (const u16*)x;
    int crazy = 0;
    for (int i = threadIdx.x; i < 512; i += 64) {
        u16 v = p[2 * i];
        int e = (v >> 7) & 0xFF;
        if (e != 0 && (e < 100 || e > 150)) crazy++;
    }
    atomicAdd(&cnt, crazy);
    __syncthreads();
    if (threadIdx.x == 0) *flag = (cnt > 128) ? 0 : 1;
}

// ---------------------------------------------------------------------------
// CSR build: histogram(+rank) -> coalesced 3-phase scan -> atomic-free scatter
// hist's atomicAdd return value IS the edge's rank within its dst node; store
// it so scatter needs no second atomic pass.
// ---------------------------------------------------------------------------
__global__ __launch_bounds__(256) void hist_kernel(
    const int* __restrict__ ei, int* __restrict__ cnt,
    int* __restrict__ rank, int E) {
    int e = blockIdx.x * 256 + threadIdx.x;
    if (e < E) rank[e] = atomicAdd(&cnt[ei[E + e]], 1);
}

__global__ __launch_bounds__(256) void scan_sums(
    const int* __restrict__ cnt, int* __restrict__ tsum, int N) {
    __shared__ int red[256];
    const int t = threadIdx.x;
    const int base = blockIdx.x * 1024;
    int s = 0;
#pragma unroll
    for (int i = 0; i < 4; ++i) {
        int idx = base + t + i * 256;
        s += (idx < N) ? cnt[idx] : 0;
    }
    red[t] = s;
    __syncthreads();
    for (int off = 128; off; off >>= 1) {
        if (t < off) red[t] += red[t + off];
        __syncthreads();
    }
    if (t == 0) tsum[blockIdx.x] = red[0];
}

__global__ __launch_bounds__(1024) void scan_tsum(
    int* __restrict__ tsum, int ntile, int* __restrict__ totalOut) {
    __shared__ int part[1024];
    const int t = threadIdx.x;
    int v = (t < ntile) ? tsum[t] : 0;
    part[t] = v;
    __syncthreads();
    for (int off = 1; off < 1024; off <<= 1) {
        int u = (t >= off) ? part[t - off] : 0;
        __syncthreads();
        part[t] += u;
        __syncthreads();
    }
    if (t < ntile) tsum[t] = part[t] - v;   // exclusive
    if (t == 1023) *totalOut = part[1023];  // row_ptr[N] = E
}

__global__ __launch_bounds__(256) void scan_down(
    const int* __restrict__ cnt, const int* __restrict__ tsumx,
    int* __restrict__ row_ptr, int N) {
    __shared__ int red[256];
    const int t = threadIdx.x;
    const int base = blockIdx.x * 1024 + t * 4;
    int4 v = make_int4(0, 0, 0, 0);
    if (base + 3 < N) {
        v = *(const int4*)(cnt + base);
    } else {
        if (base + 0 < N) v.x = cnt[base + 0];
        if (base + 1 < N) v.y = cnt[base + 1];
        if (base + 2 < N) v.z = cnt[base + 2];
        if (base + 3 < N) v.w = cnt[base + 3];
    }
    int ls = v.x + v.y + v.z + v.w;
    red[t] = ls;
    __syncthreads();
    for (int off = 1; off < 256; off <<= 1) {
        int u = (t >= off) ? red[t - off] : 0;
        __syncthreads();
        red[t] += u;
        __syncthreads();
    }
    int excl = (t == 0 ? 0 : red[t - 1]) + tsumx[blockIdx.x];
    int r0 = excl, r1 = r0 + v.x, r2 = r1 + v.y, r3 = r2 + v.z;
    if (base + 3 < N) {
        *(int4*)(row_ptr + base) = make_int4(r0, r1, r2, r3);
    } else {
        if (base + 0 < N) row_ptr[base + 0] = r0;
        if (base + 1 < N) row_ptr[base + 1] = r1;
        if (base + 2 < N) row_ptr[base + 2] = r2;
        if (base + 3 < N) row_ptr[base + 3] = r3;
    }
}

// atomic-free scatter: slot = row_ptr[dst] + rank[e]; NT store (skip RFO;
// pairs lines are dead in cache until agg reads them much later)
__global__ __launch_bounds__(256) void scatter_kernel(
    const int* __restrict__ ei, const int* __restrict__ row_ptr,
    const int* __restrict__ rank, int2* __restrict__ pairs, int E) {
    int e = blockIdx.x * 256 + threadIdx.x;
    if (e < E) {
        int dst = ei[E + e];
        int slot = row_ptr[dst] + rank[e];
        long pr = ((long)ei[e] << 32) | (unsigned int)e;   // {.x=e, .y=src}
        __builtin_nontemporal_store(pr, (long*)(pairs + slot));
    }
}

// ---------------------------------------------------------------------------
// K2: pre-transpose weights to bf16 in workspace
// ---------------------------------------------------------------------------
__global__ __launch_bounds__(256) void prep_kernel(
    const void* __restrict__ We, const void* __restrict__ W1,
    const void* __restrict__ W2, u16* __restrict__ WeT,
    u16* __restrict__ W1T, u16* __restrict__ W2T, const int* __restrict__ flag) {
    const bool bf = (*flag != 0);
    const int tid = blockIdx.x * 256 + threadIdx.x;
    const int nthr = gridDim.x * 256;
    for (int i = tid; i < NDIM * EDIM; i += nthr) {
        int k = i >> 7, d = i & 127;
        WeT[d * EDIM + k] = bf ? ((const u16*)We)[i] : f2bf(((const float*)We)[i]);
    }
    for (int i = tid; i < NDIM * NDIM; i += nthr) {
        int k = i >> 7, c = i & 127;
        W1T[c * NDIM + k] = bf ? ((const u16*)W1)[i] : f2bf(((const float*)W1)[i]);
        W2T[c * NDIM + k] = bf ? ((const u16*)W2)[i] : f2bf(((const float*)W2)[i]);
    }
}

// ---------------------------------------------------------------------------
// K3: CSR aggregation (exact round-5 structure: 16-edge groups, 4 predicated
// gather slots, VGPR~60, 2048 blocks; agg output, no h0 fusion)
// ---------------------------------------------------------------------------
__global__ __launch_bounds__(256) void agg_kernel(
    const int* __restrict__ row_ptr, const int2* __restrict__ pairs,
    const void* __restrict__ edge_attr,
    const void* __restrict__ x, const u16* __restrict__ WeT,
    const void* __restrict__ be, float* __restrict__ agg, int N,
    const int* __restrict__ flag) {
    const bool bf = (*flag != 0);
    __shared__ float xsumQ[4][4][NDIM];

    const int lane = threadIdx.x & 63;
    const int wid = threadIdx.x >> 6;
    const int q = lane >> 4, l16 = lane & 15;

    bf16x8 bfr[8];
#pragma unroll
    for (int nt = 0; nt < 8; ++nt)
        bfr[nt] = *(const bf16x8*)(WeT + (nt * 16 + l16) * EDIM + q * 8);
    f32x4 biasv[8];
#pragma unroll
    for (int nt = 0; nt < 8; ++nt) {
        float bv = bf ? bf2f(((const u16*)be)[nt * 16 + l16])
                      : ((const float*)be)[nt * 16 + l16];
        biasv[nt] = (f32x4){bv, bv, bv, bv};
    }

    const int gwave = blockIdx.x * 4 + wid;
    const int nwaves = gridDim.x * 4;

    for (int n = gwave; n < N; n += nwaves) {
        const int p0 = row_ptr[n], p1 = row_ptr[n + 1];
        float part[8];
#pragma unroll
        for (int nt = 0; nt < 8; ++nt) part[nt] = 0.0f;
        float xa[8];
#pragma unroll
        for (int j = 0; j < 8; ++j) xa[j] = 0.0f;

        for (int base = p0; base < p1; base += 16) {
            const int cnt = min(16, p1 - base);
            // x-gather: quad q handles edges base+q, +4, +8, +12
            if (bf) {
#pragma unroll
                for (int u = 0; u < 4; ++u) {
                    int t = q + 4 * u;
                    if (t < cnt) {
                        long pr = __builtin_nontemporal_load((const long*)(pairs + base + t));
                        int s = (int)(pr >> 32);
                        const u16* xr = (const u16*)x + (long)s * NDIM + l16 * 8;
                        ushort4 a = *(const ushort4*)xr;
                        ushort4 b2 = *(const ushort4*)(xr + 4);
                        xa[0] += bf2f(a.x); xa[1] += bf2f(a.y);
                        xa[2] += bf2f(a.z); xa[3] += bf2f(a.w);
                        xa[4] += bf2f(b2.x); xa[5] += bf2f(b2.y);
                        xa[6] += bf2f(b2.z); xa[7] += bf2f(b2.w);
                    }
                }
            } else {
#pragma unroll
                for (int u = 0; u < 4; ++u) {
                    int t = q + 4 * u;
                    if (t < cnt) {
                        long pr = __builtin_nontemporal_load((const long*)(pairs + base + t));
                        int s = (int)(pr >> 32);
                        const float* xr = (const float*)x + (long)s * NDIM + l16 * 8;
                        float4 a = *(const float4*)xr;
                        float4 b2 = *(const float4*)(xr + 4);
                        xa[0] += a.x; xa[1] += a.y; xa[2] += a.z; xa[3] += a.w;
                        xa[4] += b2.x; xa[5] += b2.y; xa[6] += b2.z; xa[7] += b2.w;
                    }
                }
            }
            // A-frag: attr row of edge base+l16
            long pre = __builtin_nontemporal_load(
                (const long*)(pairs + min(base + l16, p1 - 1)));
            int eid = (int)pre;
            bf16x8 af;
            if (bf) {
                af = __builtin_nontemporal_load(
                    (const bf16x8*)((const u16*)edge_attr + (long)eid * EDIM + q * 8));
            } else {
                const float* ar = (const float*)edge_attr + (long)eid * EDIM + q * 8;
                f32x4 a0 = __builtin_nontemporal_load((const f32x4*)ar);
                f32x4 a1 = __builtin_nontemporal_load((const f32x4*)(ar + 4));
                af[0] = (short)f2bf(a0[0]); af[1] = (short)f2bf(a0[1]);
                af[2] = (short)f2bf(a0[2]); af[3] = (short)f2bf(a0[3]);
                af[4] = (short)f2bf(a1[0]); af[5] = (short)f2bf(a1[1]);
                af[6] = (short)f2bf(a1[2]); af[7] = (short)f2bf(a1[3]);
            }
#pragma unroll
            for (int nt = 0; nt < 8; ++nt) {
                f32x4 c = __builtin_amdgcn_mfma_f32_16x16x32_bf16(af, bfr[nt], biasv[nt], 0, 0, 0);
#pragma unroll
                for (int r = 0; r < 4; ++r)
                    if (q * 4 + r < cnt) part[nt] += fmaxf(c[r], 0.0f);
            }
        }
        // cross-quad reduce of MFMA parts
#pragma unroll
        for (int nt = 0; nt < 8; ++nt) {
            part[nt] += __shfl_xor(part[nt], 16);
            part[nt] += __shfl_xor(part[nt], 32);
        }
        // exchange x partials through LDS (per-wave slice, wave-coherent)
        *(float4*)&xsumQ[wid][q][l16 * 8 + 0] = make_float4(xa[0], xa[1], xa[2], xa[3]);
        *(float4*)&xsumQ[wid][q][l16 * 8 + 4] = make_float4(xa[4], xa[5], xa[6], xa[7]);
#pragma unroll
        for (int j = 0; j < 2; ++j) {
            int nt = 2 * q + j;
            int d = nt * 16 + l16;
            float xs = xsumQ[wid][0][d] + xsumQ[wid][1][d] +
                       xsumQ[wid][2][d] + xsumQ[wid][3][d];
            agg[(long)n * NDIM + d] = part[nt] + xs;
        }
    }
}

// ---------------------------------------------------------------------------
// split h -> bf16 hi+lo in LDS (fp32-accurate through 2 MFMAs)
// ---------------------------------------------------------------------------
__device__ __forceinline__ void split_store(u16* hHi, u16* hLo, int r, int c, float4 h) {
    ushort4 hi, lo;
    hi.x = f2bf(h.x); lo.x = f2bf(h.x - bf2f(hi.x));
    hi.y = f2bf(h.y); lo.y = f2bf(h.y - bf2f(hi.y));
    hi.z = f2bf(h.z); lo.z = f2bf(h.z - bf2f(hi.z));
    hi.w = f2bf(h.w); lo.w = f2bf(h.w - bf2f(hi.w));
    *(ushort4*)&hHi[r * HSTR + c] = hi;
    *(ushort4*)&hLo[r * HSTR + c] = lo;
}

// ---------------------------------------------------------------------------
// K4: h0 = (1+eps)*x + agg ; h1 = h0 @ W1 + b1 ; split-atomic col stats.
// ---------------------------------------------------------------------------
__global__ __launch_bounds__(256) void gemm1_kernel(
    const void* __restrict__ x, const float* __restrict__ agg,
    const void* __restrict__ eps_p, const u16* __restrict__ WT,
    const void* __restrict__ b, float* __restrict__ hout,
    float* __restrict__ stats, int M, const int* __restrict__ flag) {
    const bool bf = (*flag != 0);
    __shared__ u16 hHi[64 * HSTR];
    __shared__ u16 hLo[64 * HSTR];
    __shared__ float redS[4][NDIM];
    __shared__ float redQ[4][NDIM];

    const int tid = threadIdx.x;
    const int row0 = blockIdx.x * 64;
    const int cp = (blockIdx.x & (NSPLIT - 1)) * 256;
    const float onepeps = 1.0f + (bf ? bf2f(((const u16*)eps_p)[0])
                                     : ((const float*)eps_p)[0]);

#pragma unroll
    for (int i = 0; i < 8; ++i) {
        int idx = (tid + i * 256) * 4;
        int r = idx >> 7, c = idx & 127;
        int row = row0 + r;
        float4 h = make_float4(0.f, 0.f, 0.f, 0.f);
        if (row < M) {
            f32x4 agv = __builtin_nontemporal_load((const f32x4*)(agg + (long)row * NDIM + c));
            float4 ag = make_float4(agv[0], agv[1], agv[2], agv[3]);
            float4 xv;
            if (bf) {
                ushort4 u = *(const ushort4*)((const u16*)x + (long)row * NDIM + c);
                xv = make_float4(bf2f(u.x), bf2f(u.y), bf2f(u.z), bf2f(u.w));
            } else {
                xv = *(const float4*)((const float*)x + (long)row * NDIM + c);
            }
            h = make_float4(onepeps * xv.x + ag.x, onepeps * xv.y + ag.y,
                            onepeps * xv.z + ag.z, onepeps * xv.w + ag.w);
        }
        split_store(hHi, hLo, r, c, h);
    }
    __syncthreads();

    const int lane = tid & 63, w = tid >> 6;
    const int q = lane >> 4, l16 = lane & 15;

    f32x4 acc[8];
#pragma unroll
    for (int nt = 0; nt < 8; ++nt) {
        float bj = bf ? bf2f(((const u16*)b)[nt * 16 + l16])
                      : ((const float*)b)[nt * 16 + l16];
        acc[nt] = (f32x4){bj, bj, bj, bj};
    }
#pragma unroll
    for (int ks = 0; ks < 4; ++ks) {
        bf16x8 aHi = *(const bf16x8*)&hHi[(w * 16 + l16) * HSTR + ks * 32 + q * 8];
        bf16x8 aLo = *(const bf16x8*)&hLo[(w * 16 + l16) * HSTR + ks * 32 + q * 8];
#pragma unroll
        for (int nt = 0; nt < 8; ++nt) {
            bf16x8 bfr = *(const bf16x8*)(WT + (long)(nt * 16 + l16) * NDIM + ks * 32 + q * 8);
            acc[nt] = __builtin_amdgcn_mfma_f32_16x16x32_bf16(aHi, bfr, acc[nt], 0, 0, 0);
            acc[nt] = __builtin_amdgcn_mfma_f32_16x16x32_bf16(aLo, bfr, acc[nt], 0, 0, 0);
        }
    }

#pragma unroll
    for (int nt = 0; nt < 8; ++nt) {
        float s = 0.f, qs = 0.f;
#pragma unroll
        for (int r = 0; r < 4; ++r) {
            int row = row0 + w * 16 + q * 4 + r;
            if (row < M) {
                float v = acc[nt][r];
                hout[(long)row * NDIM + nt * 16 + l16] = v;
                s += v; qs += v * v;
            }
        }
        s += __shfl_xor(s, 16);  s += __shfl_xor(s, 32);
        qs += __shfl_xor(qs, 16); qs += __shfl_xor(qs, 32);
        if (nt == 2 * q || nt == 2 * q + 1) {
            redS[w][nt * 16 + l16] = s;
            redQ[w][nt * 16 + l16] = qs;
        }
    }
    __syncthreads();
    if (tid < NDIM) {
        atomicAdd(&stats[cp + tid], redS[0][tid] + redS[1][tid] + redS[2][tid] + redS[3][tid]);
    } else {
        int c = tid - NDIM;
        atomicAdd(&stats[cp + NDIM + c], redQ[0][c] + redQ[1][c] + redQ[2][c] + redQ[3][c]);
    }
}

// ---------------------------------------------------------------------------
// K5: a = relu(BN1(h1)) ; h2 = a @ W2 + b2 ; split-atomic col stats.
// ---------------------------------------------------------------------------
__global__ __launch_bounds__(256) void gemm2_kernel(
    const float* __restrict__ h1, const float* __restrict__ statsIn,
    const void* __restrict__ g, const void* __restrict__ beta,
    const u16* __restrict__ WT, const void* __restrict__ b,
    float* __restrict__ hout, float* __restrict__ stats, int M,
    const int* __restrict__ flag) {
    const bool bf = (*flag != 0);
    __shared__ u16 hHi[64 * HSTR];
    __shared__ u16 hLo[64 * HSTR];
    __shared__ float redS[4][NDIM];
    __shared__ float redQ[4][NDIM];
    __shared__ float scaleL[NDIM];
    __shared__ float shiftL[NDIM];

    const int tid = threadIdx.x;
    const int row0 = blockIdx.x * 64;
    const int cp = (blockIdx.x & (NSPLIT - 1)) * 256;

    if (tid < NDIM) {
        float s = 0.f, qv = 0.f;
#pragma unroll 4
        for (int c = 0; c < NSPLIT; ++c) {
            s += statsIn[c * 256 + tid];
            qv += statsIn[c * 256 + NDIM + tid];
        }
        float invM = 1.0f / (float)M;
        float mean = s * invM;
        float var = fmaxf(qv * invM - mean * mean, 0.0f) + 1e-5f;
        float gv = bf ? bf2f(((const u16*)g)[tid]) : ((const float*)g)[tid];
        float bv = bf ? bf2f(((const u16*)beta)[tid]) : ((const float*)beta)[tid];
        float sc = gv * rsqrtf(var);
        scaleL[tid] = sc;
        shiftL[tid] = bv - mean * sc;
    }
    __syncthreads();

#pragma unroll
    for (int i = 0; i < 8; ++i) {
        int idx = (tid + i * 256) * 4;
        int r = idx >> 7, c = idx & 127;
        int row = row0 + r;
        float4 h = make_float4(0.f, 0.f, 0.f, 0.f);
        if (row < M) {
            f32x4 hvv = __builtin_nontemporal_load((const f32x4*)(h1 + (long)row * NDIM + c));
            h.x = fmaxf(hvv[0] * scaleL[c + 0] + shiftL[c + 0], 0.0f);
            h.y = fmaxf(hvv[1] * scaleL[c + 1] + shiftL[c + 1], 0.0f);
            h.z = fmaxf(hvv[2] * scaleL[c + 2] + shiftL[c + 2], 0.0f);
            h.w = fmaxf(hvv[3] * scaleL[c + 3] + shiftL[c + 3], 0.0f);
        }
        split_store(hHi, hLo, r, c, h);
    }
    __syncthreads();

    const int lane = tid & 63, w = tid >> 6;
    const int q = lane >> 4, l16 = lane & 15;

    f32x4 acc[8];
#pragma unroll
    for (int nt = 0; nt < 8; ++nt) {
        float bj = bf ? bf2f(((const u16*)b)[nt * 16 + l16])
                      : ((const float*)b)[nt * 16 + l16];
        acc[nt] = (f32x4){bj, bj, bj, bj};
    }
#pragma unroll
    for (int ks = 0; ks < 4; ++ks) {
        bf16x8 aHi = *(const bf16x8*)&hHi[(w * 16 + l16) * HSTR + ks * 32 + q * 8];
        bf16x8 aLo = *(const bf16x8*)&hLo[(w * 16 + l16) * HSTR + ks * 32 + q * 8];
#pragma unroll
        for (int nt = 0; nt < 8; ++nt) {
            bf16x8 bfr = *(const bf16x8*)(WT + (long)(nt * 16 + l16) * NDIM + ks * 32 + q * 8);
            acc[nt] = __builtin_amdgcn_mfma_f32_16x16x32_bf16(aHi, bfr, acc[nt], 0, 0, 0);
            acc[nt] = __builtin_amdgcn_mfma_f32_16x16x32_bf16(aLo, bfr, acc[nt], 0, 0, 0);
        }
    }

#pragma unroll
    for (int nt = 0; nt < 8; ++nt) {
        float s = 0.f, qs = 0.f;
#pragma unroll
        for (int r = 0; r < 4; ++r) {
            int row = row0 + w * 16 + q * 4 + r;
            if (row < M) {
                float v = acc[nt][r];
                hout[(long)row * NDIM + nt * 16 + l16] = v;
                s += v; qs += v * v;
            }
        }
        s += __shfl_xor(s, 16);  s += __shfl_xor(s, 32);
        qs += __shfl_xor(qs, 16); qs += __shfl_xor(qs, 32);
        if (nt == 2 * q || nt == 2 * q + 1) {
            redS[w][nt * 16 + l16] = s;
            redQ[w][nt * 16 + l16] = qs;
        }
    }
    __syncthreads();
    if (tid < NDIM) {
        atomicAdd(&stats[cp + tid], redS[0][tid] + redS[1][tid] + redS[2][tid] + redS[3][tid]);
    } else {
        int c = tid - NDIM;
        atomicAdd(&stats[cp + NDIM + c], redQ[0][c] + redQ[1][c] + redQ[2][c] + redQ[3][c]);
    }
}

// ---------------------------------------------------------------------------
// K6: out = relu(BN2(h2)) -> output dtype
// ---------------------------------------------------------------------------
__global__ __launch_bounds__(256) void bn2_out_kernel(
    const float* __restrict__ h2, const float* __restrict__ statsIn,
    const void* __restrict__ g, const void* __restrict__ beta,
    void* __restrict__ out, int M, const int* __restrict__ flag) {
    const bool bf = (*flag != 0);
    __shared__ float scaleL[NDIM];
    __shared__ float shiftL[NDIM];
    const int tid = threadIdx.x;
    if (tid < NDIM) {
        float s = 0.f, qv = 0.f;
#pragma unroll 4
        for (int c = 0; c < NSPLIT; ++c) {
            s += statsIn[c * 256 + tid];
            qv += statsIn[c * 256 + NDIM + tid];
        }
        float invM = 1.0f / (float)M;
        float mean = s * invM;
        float var = fmaxf(qv * invM - mean * mean, 0.0f) + 1e-5f;
        float gv = bf ? bf2f(((const u16*)g)[tid]) : ((const float*)g)[tid];
        float bv = bf ? bf2f(((const u16*)beta)[tid]) : ((const float*)beta)[tid];
        float sc = gv * rsqrtf(var);
        scaleL[tid] = sc;
        shiftL[tid] = bv - mean * sc;
    }
    __syncthreads();

    const int n4 = M * NDIM / 4;
    for (int i = blockIdx.x * 256 + tid; i < n4; i += gridDim.x * 256) {
        int c = (i & 31) * 4;
        f32x4 hv = __builtin_nontemporal_load((const f32x4*)(h2 + (long)i * 4));
        float o0 = fmaxf(hv[0] * scaleL[c + 0] + shiftL[c + 0], 0.0f);
        float o1 = fmaxf(hv[1] * scaleL[c + 1] + shiftL[c + 1], 0.0f);
        float o2 = fmaxf(hv[2] * scaleL[c + 2] + shiftL[c + 2], 0.0f);
        float o3 = fmaxf(hv[3] * scaleL[c + 3] + shiftL[c + 3], 0.0f);
        if (bf) {
            u16x4 o;
            o.x = f2bf(o0); o.y = f2bf(o1); o.z = f2bf(o2); o.w = f2bf(o3);
            __builtin_nontemporal_store(o, (u16x4*)((u16*)out + (long)i * 4));
        } else {
            f32x4 o = (f32x4){o0, o1, o2, o3};
            __builtin_nontemporal_store(o, (f32x4*)((float*)out + (long)i * 4));
        }
    }
}

extern "C" void kernel_launch(void* const* d_in, const int* in_sizes, int n_in,
                              void* d_out, int out_size, void* d_ws, size_t ws_size,
                              hipStream_t stream) {
    const void* x         = d_in[0];
    const int*  ei        = (const int*)d_in[1];
    const void* edge_attr = d_in[2];
    const void* eps_p     = d_in[3];
    const void* We        = d_in[4];
    const void* be        = d_in[5];
    const void* W1        = d_in[6];
    const void* b1        = d_in[7];
    const void* g1        = d_in[8];
    const void* beta1     = d_in[9];
    const void* W2        = d_in[10];
    const void* b2        = d_in[11];
    const void* g2        = d_in[12];
    const void* beta2     = d_in[13];

    int N = in_sizes[0] / NDIM;                // 50000
    int E = in_sizes[1] / 2;                   // 800000
    const size_t nd = (size_t)N * NDIM;

    float* agg    = (float*)d_ws;              // [nd]; reused as h2
    float* h1     = agg + nd;                  // [nd]
    float* stats1 = h1 + nd;                   // [NSPLIT*256]
    float* stats2 = stats1 + NSPLIT * 256;     // [NSPLIT*256]
    int*   flag   = (int*)(stats2 + NSPLIT * 256); // [4]
    u16*   WeT    = (u16*)(flag + 4);          // [128*32]
    u16*   W1T    = WeT + NDIM * EDIM;         // [128*128]
    u16*   W2T    = W1T + NDIM * NDIM;         // [128*128]
    int*   tsum   = (int*)(W2T + NDIM * NDIM); // [1024]
    float* h2     = agg;                       // reuse

    // CSR scratch overlaid on h1 (dead before gemm1 writes h1)
    int2* pairs   = (int2*)h1;                 // [E]
    int* cnt      = (int*)(pairs + E);         // [N]
    int* row_ptr  = cnt + N;                   // [N+1]
    int* rank     = row_ptr + N + 1;           // [E]

    detect_kernel<<<1, 64, 0, stream>>>(x, flag);
    hipMemsetAsync(stats1, 0, 2 * NSPLIT * 256 * sizeof(float), stream);
    hipMemsetAsync(cnt, 0, (size_t)N * sizeof(int), stream);

    const int eblk = (E + 255) / 256;
    const int ntile = (N + 1023) / 1024;
    hist_kernel<<<eblk, 256, 0, stream>>>(ei, cnt, rank, E);
    scan_sums<<<ntile, 256, 0, stream>>>(cnt, tsum, N);
    scan_tsum<<<1, 1024, 0, stream>>>(tsum, ntile, &row_ptr[N]);
    scan_down<<<ntile, 256, 0, stream>>>(cnt, tsum, row_ptr, N);
    scatter_kernel<<<eblk, 256, 0, stream>>>(ei, row_ptr, rank, pairs, E);

    prep_kernel<<<64, 256, 0, stream>>>(We, W1, W2, WeT, W1T, W2T, flag);

    agg_kernel<<<2048, 256, 0, stream>>>(row_ptr, pairs, edge_attr, x,
                                         WeT, be, agg, N, flag);

    const int nblk = (N + 63) / 64;
    gemm1_kernel<<<nblk, 256, 0, stream>>>(x, agg, eps_p, W1T, b1, h1, stats1, N, flag);
    gemm2_kernel<<<nblk, 256, 0, stream>>>(h1, stats1, g1, beta1, W2T, b2, h2, stats2, N, flag);
    bn2_out_kernel<<<2048, 256, 0, stream>>>(h2, stats2, g2, beta2, d_out, N, flag);
}

// Round 10
// 425.559 us; speedup vs baseline: 1.1343x; 1.0151x over previous
//
#include <hip/hip_runtime.h>
#include <hip/hip_bf16.h>

typedef unsigned short u16;
typedef __attribute__((ext_vector_type(8))) short bf16x8;
typedef __attribute__((ext_vector_type(4))) float f32x4;
typedef __attribute__((ext_vector_type(4))) unsigned short u16x4;

#define NDIM 128
#define EDIM 32
#define HSTR 136     // gemm h LDS stride (u16): 16B aligned, 2-way banks (free)
#define NSPLIT 32    // stats atomic split copies

__device__ __forceinline__ float bf2f(u16 u) {
    union { unsigned int i; float f; } v; v.i = ((unsigned int)u) << 16; return v.f;
}
__device__ __forceinline__ u16 f2bf(float f) {
    __hip_bfloat16 h = __float2bfloat16(f);
    return *reinterpret_cast<u16*>(&h);
}

// dtype detection, computed identically by any block that needs it:
// examine first 1024 u16 of x (512 even-index samples); bf16 iff few
// "crazy" exponents. Deterministic -> all blocks agree.
__device__ __forceinline__ bool detect_bf16_local(const void* x, int* lds_cnt) {
    if (threadIdx.x == 0) *lds_cnt = 0;
    __syncthreads();
    const u16* p = (const u16*)x;
    int crazy = 0;
    for (int i = threadIdx.x; i < 512; i += blockDim.x) {
        u16 v = p[2 * i];
        int e = (v >> 7) & 0xFF;
        if (e != 0 && (e < 100 || e > 150)) crazy++;
    }
    atomicAdd(lds_cnt, crazy);
    __syncthreads();
    return (*lds_cnt <= 128);
}

// ---------------------------------------------------------------------------
// CSR build: histogram(+rank) -> coalesced 2-phase scan -> atomic-free scatter
// ---------------------------------------------------------------------------
__global__ __launch_bounds__(256) void hist_kernel(
    const int* __restrict__ ei, int* __restrict__ cnt,
    int* __restrict__ rank, int E) {
    int e = blockIdx.x * 256 + threadIdx.x;
    if (e < E) rank[e] = atomicAdd(&cnt[ei[E + e]], 1);
}

__global__ __launch_bounds__(256) void scan_sums(
    const int* __restrict__ cnt, int* __restrict__ tsum, int N) {
    __shared__ int red[256];
    const int t = threadIdx.x;
    const int base = blockIdx.x * 1024;
    int s = 0;
#pragma unroll
    for (int i = 0; i < 4; ++i) {
        int idx = base + t + i * 256;
        s += (idx < N) ? cnt[idx] : 0;
    }
    red[t] = s;
    __syncthreads();
    for (int off = 128; off; off >>= 1) {
        if (t < off) red[t] += red[t + off];
        __syncthreads();
    }
    if (t == 0) tsum[blockIdx.x] = red[0];
}

// down-sweep; each block computes its own tile offset from raw tsum
// (ntile <= 256; 49 here, L2-hot). row_ptr[N] = E written directly.
__global__ __launch_bounds__(256) void scan_down(
    const int* __restrict__ cnt, const int* __restrict__ tsum,
    int* __restrict__ row_ptr, int N, int E) {
    __shared__ int red[256];
    const int t = threadIdx.x;

    // tile offset = sum of tsum[0..blockIdx)
    red[t] = (t < blockIdx.x) ? tsum[t] : 0;
    __syncthreads();
    for (int off = 128; off; off >>= 1) {
        if (t < off) red[t] += red[t + off];
        __syncthreads();
    }
    const int tileoff = red[0];
    __syncthreads();

    const int base = blockIdx.x * 1024 + t * 4;
    int4 v = make_int4(0, 0, 0, 0);
    if (base + 3 < N) {
        v = *(const int4*)(cnt + base);
    } else {
        if (base + 0 < N) v.x = cnt[base + 0];
        if (base + 1 < N) v.y = cnt[base + 1];
        if (base + 2 < N) v.z = cnt[base + 2];
        if (base + 3 < N) v.w = cnt[base + 3];
    }
    int ls = v.x + v.y + v.z + v.w;
    red[t] = ls;
    __syncthreads();
    for (int off = 1; off < 256; off <<= 1) {
        int u = (t >= off) ? red[t - off] : 0;
        __syncthreads();
        red[t] += u;
        __syncthreads();
    }
    int excl = (t == 0 ? 0 : red[t - 1]) + tileoff;
    int r0 = excl, r1 = r0 + v.x, r2 = r1 + v.y, r3 = r2 + v.z;
    if (base + 3 < N) {
        *(int4*)(row_ptr + base) = make_int4(r0, r1, r2, r3);
    } else {
        if (base + 0 < N) row_ptr[base + 0] = r0;
        if (base + 1 < N) row_ptr[base + 1] = r1;
        if (base + 2 < N) row_ptr[base + 2] = r2;
        if (base + 3 < N) row_ptr[base + 3] = r3;
    }
    if (blockIdx.x == 0 && t == 0) row_ptr[N] = E;
}

// atomic-free scatter: slot = row_ptr[dst] + rank[e]; NT store (skip RFO)
__global__ __launch_bounds__(256) void scatter_kernel(
    const int* __restrict__ ei, const int* __restrict__ row_ptr,
    const int* __restrict__ rank, int2* __restrict__ pairs, int E) {
    int e = blockIdx.x * 256 + threadIdx.x;
    if (e < E) {
        int dst = ei[E + e];
        int slot = row_ptr[dst] + rank[e];
        long pr = ((long)ei[e] << 32) | (unsigned int)e;   // {.x=e, .y=src}
        __builtin_nontemporal_store(pr, (long*)(pairs + slot));
    }
}

// ---------------------------------------------------------------------------
// K2: dtype detect (local) + pre-transpose weights to bf16 in workspace.
// Block 0 publishes flag for downstream kernels.
// ---------------------------------------------------------------------------
__global__ __launch_bounds__(256) void prep_kernel(
    const void* __restrict__ x,
    const void* __restrict__ We, const void* __restrict__ W1,
    const void* __restrict__ W2, u16* __restrict__ WeT,
    u16* __restrict__ W1T, u16* __restrict__ W2T, int* __restrict__ flag) {
    __shared__ int cnt_s;
    const bool bf = detect_bf16_local(x, &cnt_s);
    if (blockIdx.x == 0 && threadIdx.x == 0) *flag = bf ? 1 : 0;

    const int tid = blockIdx.x * 256 + threadIdx.x;
    const int nthr = gridDim.x * 256;
    for (int i = tid; i < NDIM * EDIM; i += nthr) {
        int k = i >> 7, d = i & 127;
        WeT[d * EDIM + k] = bf ? ((const u16*)We)[i] : f2bf(((const float*)We)[i]);
    }
    for (int i = tid; i < NDIM * NDIM; i += nthr) {
        int k = i >> 7, c = i & 127;
        W1T[c * NDIM + k] = bf ? ((const u16*)W1)[i] : f2bf(((const float*)W1)[i]);
        W2T[c * NDIM + k] = bf ? ((const u16*)W2)[i] : f2bf(((const float*)W2)[i]);
    }
}

// ---------------------------------------------------------------------------
// K3: CSR aggregation (verified round-9 structure, unchanged)
// ---------------------------------------------------------------------------
__global__ __launch_bounds__(256) void agg_kernel(
    const int* __restrict__ row_ptr, const int2* __restrict__ pairs,
    const void* __restrict__ edge_attr,
    const void* __restrict__ x, const u16* __restrict__ WeT,
    const void* __restrict__ be, float* __restrict__ agg, int N,
    const int* __restrict__ flag) {
    const bool bf = (*flag != 0);
    __shared__ float xsumQ[4][4][NDIM];

    const int lane = threadIdx.x & 63;
    const int wid = threadIdx.x >> 6;
    const int q = lane >> 4, l16 = lane & 15;

    bf16x8 bfr[8];
#pragma unroll
    for (int nt = 0; nt < 8; ++nt)
        bfr[nt] = *(const bf16x8*)(WeT + (nt * 16 + l16) * EDIM + q * 8);
    f32x4 biasv[8];
#pragma unroll
    for (int nt = 0; nt < 8; ++nt) {
        float bv = bf ? bf2f(((const u16*)be)[nt * 16 + l16])
                      : ((const float*)be)[nt * 16 + l16];
        biasv[nt] = (f32x4){bv, bv, bv, bv};
    }

    const int gwave = blockIdx.x * 4 + wid;
    const int nwaves = gridDim.x * 4;

    for (int n = gwave; n < N; n += nwaves) {
        const int p0 = row_ptr[n], p1 = row_ptr[n + 1];
        float part[8];
#pragma unroll
        for (int nt = 0; nt < 8; ++nt) part[nt] = 0.0f;
        float xa[8];
#pragma unroll
        for (int j = 0; j < 8; ++j) xa[j] = 0.0f;

        for (int base = p0; base < p1; base += 16) {
            const int cnt = min(16, p1 - base);
            // x-gather: quad q handles edges base+q, +4, +8, +12
            if (bf) {
#pragma unroll
                for (int u = 0; u < 4; ++u) {
                    int t = q + 4 * u;
                    if (t < cnt) {
                        long pr = __builtin_nontemporal_load((const long*)(pairs + base + t));
                        int s = (int)(pr >> 32);
                        const u16* xr = (const u16*)x + (long)s * NDIM + l16 * 8;
                        ushort4 a = *(const ushort4*)xr;
                        ushort4 b2 = *(const ushort4*)(xr + 4);
                        xa[0] += bf2f(a.x); xa[1] += bf2f(a.y);
                        xa[2] += bf2f(a.z); xa[3] += bf2f(a.w);
                        xa[4] += bf2f(b2.x); xa[5] += bf2f(b2.y);
                        xa[6] += bf2f(b2.z); xa[7] += bf2f(b2.w);
                    }
                }
            } else {
#pragma unroll
                for (int u = 0; u < 4; ++u) {
                    int t = q + 4 * u;
                    if (t < cnt) {
                        long pr = __builtin_nontemporal_load((const long*)(pairs + base + t));
                        int s = (int)(pr >> 32);
                        const float* xr = (const float*)x + (long)s * NDIM + l16 * 8;
                        float4 a = *(const float4*)xr;
                        float4 b2 = *(const float4*)(xr + 4);
                        xa[0] += a.x; xa[1] += a.y; xa[2] += a.z; xa[3] += a.w;
                        xa[4] += b2.x; xa[5] += b2.y; xa[6] += b2.z; xa[7] += b2.w;
                    }
                }
            }
            // A-frag: attr row of edge base+l16
            long pre = __builtin_nontemporal_load(
                (const long*)(pairs + min(base + l16, p1 - 1)));
            int eid = (int)pre;
            bf16x8 af;
            if (bf) {
                af = __builtin_nontemporal_load(
                    (const bf16x8*)((const u16*)edge_attr + (long)eid * EDIM + q * 8));
            } else {
                const float* ar = (const float*)edge_attr + (long)eid * EDIM + q * 8;
                f32x4 a0 = __builtin_nontemporal_load((const f32x4*)ar);
                f32x4 a1 = __builtin_nontemporal_load((const f32x4*)(ar + 4));
                af[0] = (short)f2bf(a0[0]); af[1] = (short)f2bf(a0[1]);
                af[2] = (short)f2bf(a0[2]); af[3] = (short)f2bf(a0[3]);
                af[4] = (short)f2bf(a1[0]); af[5] = (short)f2bf(a1[1]);
                af[6] = (short)f2bf(a1[2]); af[7] = (short)f2bf(a1[3]);
            }
#pragma unroll
            for (int nt = 0; nt < 8; ++nt) {
                f32x4 c = __builtin_amdgcn_mfma_f32_16x16x32_bf16(af, bfr[nt], biasv[nt], 0, 0, 0);
#pragma unroll
                for (int r = 0; r < 4; ++r)
                    if (q * 4 + r < cnt) part[nt] += fmaxf(c[r], 0.0f);
            }
        }
        // cross-quad reduce of MFMA parts
#pragma unroll
        for (int nt = 0; nt < 8; ++nt) {
            part[nt] += __shfl_xor(part[nt], 16);
            part[nt] += __shfl_xor(part[nt], 32);
        }
        // exchange x partials through LDS (per-wave slice, wave-coherent)
        *(float4*)&xsumQ[wid][q][l16 * 8 + 0] = make_float4(xa[0], xa[1], xa[2], xa[3]);
        *(float4*)&xsumQ[wid][q][l16 * 8 + 4] = make_float4(xa[4], xa[5], xa[6], xa[7]);
#pragma unroll
        for (int j = 0; j < 2; ++j) {
            int nt = 2 * q + j;
            int d = nt * 16 + l16;
            float xs = xsumQ[wid][0][d] + xsumQ[wid][1][d] +
                       xsumQ[wid][2][d] + xsumQ[wid][3][d];
            agg[(long)n * NDIM + d] = part[nt] + xs;
        }
    }
}

// ---------------------------------------------------------------------------
// split h -> bf16 hi+lo in LDS (fp32-accurate through 2 MFMAs)
// ---------------------------------------------------------------------------
__device__ __forceinline__ void split_store(u16* hHi, u16* hLo, int r, int c, float4 h) {
    ushort4 hi, lo;
    hi.x = f2bf(h.x); lo.x = f2bf(h.x - bf2f(hi.x));
    hi.y = f2bf(h.y); lo.y = f2bf(h.y - bf2f(hi.y));
    hi.z = f2bf(h.z); lo.z = f2bf(h.z - bf2f(hi.z));
    hi.w = f2bf(h.w); lo.w = f2bf(h.w - bf2f(hi.w));
    *(ushort4*)&hHi[r * HSTR + c] = hi;
    *(ushort4*)&hLo[r * HSTR + c] = lo;
}

// ---------------------------------------------------------------------------
// K4: h0 = (1+eps)*x + agg ; h1 = h0 @ W1 + b1 ; split-atomic col stats.
// ---------------------------------------------------------------------------
__global__ __launch_bounds__(256) void gemm1_kernel(
    const void* __restrict__ x, const float* __restrict__ agg,
    const void* __restrict__ eps_p, const u16* __restrict__ WT,
    const void* __restrict__ b, float* __restrict__ hout,
    float* __restrict__ stats, int M, const int* __restrict__ flag) {
    const bool bf = (*flag != 0);
    __shared__ u16 hHi[64 * HSTR];
    __shared__ u16 hLo[64 * HSTR];
    __shared__ float redS[4][NDIM];
    __shared__ float redQ[4][NDIM];

    const int tid = threadIdx.x;
    const int row0 = blockIdx.x * 64;
    const int cp = (blockIdx.x & (NSPLIT - 1)) * 256;
    const float onepeps = 1.0f + (bf ? bf2f(((const u16*)eps_p)[0])
                                     : ((const float*)eps_p)[0]);

#pragma unroll
    for (int i = 0; i < 8; ++i) {
        int idx = (tid + i * 256) * 4;
        int r = idx >> 7, c = idx & 127;
        int row = row0 + r;
        float4 h = make_float4(0.f, 0.f, 0.f, 0.f);
        if (row < M) {
            f32x4 agv = __builtin_nontemporal_load((const f32x4*)(agg + (long)row * NDIM + c));
            float4 ag = make_float4(agv[0], agv[1], agv[2], agv[3]);
            float4 xv;
            if (bf) {
                ushort4 u = *(const ushort4*)((const u16*)x + (long)row * NDIM + c);
                xv = make_float4(bf2f(u.x), bf2f(u.y), bf2f(u.z), bf2f(u.w));
            } else {
                xv = *(const float4*)((const float*)x + (long)row * NDIM + c);
            }
            h = make_float4(onepeps * xv.x + ag.x, onepeps * xv.y + ag.y,
                            onepeps * xv.z + ag.z, onepeps * xv.w + ag.w);
        }
        split_store(hHi, hLo, r, c, h);
    }
    __syncthreads();

    const int lane = tid & 63, w = tid >> 6;
    const int q = lane >> 4, l16 = lane & 15;

    f32x4 acc[8];
#pragma unroll
    for (int nt = 0; nt < 8; ++nt) {
        float bj = bf ? bf2f(((const u16*)b)[nt * 16 + l16])
                      : ((const float*)b)[nt * 16 + l16];
        acc[nt] = (f32x4){bj, bj, bj, bj};
    }
#pragma unroll
    for (int ks = 0; ks < 4; ++ks) {
        bf16x8 aHi = *(const bf16x8*)&hHi[(w * 16 + l16) * HSTR + ks * 32 + q * 8];
        bf16x8 aLo = *(const bf16x8*)&hLo[(w * 16 + l16) * HSTR + ks * 32 + q * 8];
#pragma unroll
        for (int nt = 0; nt < 8; ++nt) {
            bf16x8 bfr = *(const bf16x8*)(WT + (long)(nt * 16 + l16) * NDIM + ks * 32 + q * 8);
            acc[nt] = __builtin_amdgcn_mfma_f32_16x16x32_bf16(aHi, bfr, acc[nt], 0, 0, 0);
            acc[nt] = __builtin_amdgcn_mfma_f32_16x16x32_bf16(aLo, bfr, acc[nt], 0, 0, 0);
        }
    }

#pragma unroll
    for (int nt = 0; nt < 8; ++nt) {
        float s = 0.f, qs = 0.f;
#pragma unroll
        for (int r = 0; r < 4; ++r) {
            int row = row0 + w * 16 + q * 4 + r;
            if (row < M) {
                float v = acc[nt][r];
                hout[(long)row * NDIM + nt * 16 + l16] = v;
                s += v; qs += v * v;
            }
        }
        s += __shfl_xor(s, 16);  s += __shfl_xor(s, 32);
        qs += __shfl_xor(qs, 16); qs += __shfl_xor(qs, 32);
        if (nt == 2 * q || nt == 2 * q + 1) {
            redS[w][nt * 16 + l16] = s;
            redQ[w][nt * 16 + l16] = qs;
        }
    }
    __syncthreads();
    if (tid < NDIM) {
        atomicAdd(&stats[cp + tid], redS[0][tid] + redS[1][tid] + redS[2][tid] + redS[3][tid]);
    } else {
        int c = tid - NDIM;
        atomicAdd(&stats[cp + NDIM + c], redQ[0][c] + redQ[1][c] + redQ[2][c] + redQ[3][c]);
    }
}

// ---------------------------------------------------------------------------
// K5: a = relu(BN1(h1)) ; h2 = a @ W2 + b2 ; split-atomic col stats.
// ---------------------------------------------------------------------------
__global__ __launch_bounds__(256) void gemm2_kernel(
    const float* __restrict__ h1, const float* __restrict__ statsIn,
    const void* __restrict__ g, const void* __restrict__ beta,
    const u16* __restrict__ WT, const void* __restrict__ b,
    float* __restrict__ hout, float* __restrict__ stats, int M,
    const int* __restrict__ flag) {
    const bool bf = (*flag != 0);
    __shared__ u16 hHi[64 * HSTR];
    __shared__ u16 hLo[64 * HSTR];
    __shared__ float redS[4][NDIM];
    __shared__ float redQ[4][NDIM];
    __shared__ float scaleL[NDIM];
    __shared__ float shiftL[NDIM];

    const int tid = threadIdx.x;
    const int row0 = blockIdx.x * 64;
    const int cp = (blockIdx.x & (NSPLIT - 1)) * 256;

    if (tid < NDIM) {
        float s = 0.f, qv = 0.f;
#pragma unroll 4
        for (int c = 0; c < NSPLIT; ++c) {
            s += statsIn[c * 256 + tid];
            qv += statsIn[c * 256 + NDIM + tid];
        }
        float invM = 1.0f / (float)M;
        float mean = s * invM;
        float var = fmaxf(qv * invM - mean * mean, 0.0f) + 1e-5f;
        float gv = bf ? bf2f(((const u16*)g)[tid]) : ((const float*)g)[tid];
        float bv = bf ? bf2f(((const u16*)beta)[tid]) : ((const float*)beta)[tid];
        float sc = gv * rsqrtf(var);
        scaleL[tid] = sc;
        shiftL[tid] = bv - mean * sc;
    }
    __syncthreads();

#pragma unroll
    for (int i = 0; i < 8; ++i) {
        int idx = (tid + i * 256) * 4;
        int r = idx >> 7, c = idx & 127;
        int row = row0 + r;
        float4 h = make_float4(0.f, 0.f, 0.f, 0.f);
        if (row < M) {
            f32x4 hvv = __builtin_nontemporal_load((const f32x4*)(h1 + (long)row * NDIM + c));
            h.x = fmaxf(hvv[0] * scaleL[c + 0] + shiftL[c + 0], 0.0f);
            h.y = fmaxf(hvv[1] * scaleL[c + 1] + shiftL[c + 1], 0.0f);
            h.z = fmaxf(hvv[2] * scaleL[c + 2] + shiftL[c + 2], 0.0f);
            h.w = fmaxf(hvv[3] * scaleL[c + 3] + shiftL[c + 3], 0.0f);
        }
        split_store(hHi, hLo, r, c, h);
    }
    __syncthreads();

    const int lane = tid & 63, w = tid >> 6;
    const int q = lane >> 4, l16 = lane & 15;

    f32x4 acc[8];
#pragma unroll
    for (int nt = 0; nt < 8; ++nt) {
        float bj = bf ? bf2f(((const u16*)b)[nt * 16 + l16])
                      : ((const float*)b)[nt * 16 + l16];
        acc[nt] = (f32x4){bj, bj, bj, bj};
    }
#pragma unroll
    for (int ks = 0; ks < 4; ++ks) {
        bf16x8 aHi = *(const bf16x8*)&hHi[(w * 16 + l16) * HSTR + ks * 32 + q * 8];
        bf16x8 aLo = *(const bf16x8*)&hLo[(w * 16 + l16) * HSTR + ks * 32 + q * 8];
#pragma unroll
        for (int nt = 0; nt < 8; ++nt) {
            bf16x8 bfr = *(const bf16x8*)(WT + (long)(nt * 16 + l16) * NDIM + ks * 32 + q * 8);
            acc[nt] = __builtin_amdgcn_mfma_f32_16x16x32_bf16(aHi, bfr, acc[nt], 0, 0, 0);
            acc[nt] = __builtin_amdgcn_mfma_f32_16x16x32_bf16(aLo, bfr, acc[nt], 0, 0, 0);
        }
    }

#pragma unroll
    for (int nt = 0; nt < 8; ++nt) {
        float s = 0.f, qs = 0.f;
#pragma unroll
        for (int r = 0; r < 4; ++r) {
            int row = row0 + w * 16 + q * 4 + r;
            if (row < M) {
                float v = acc[nt][r];
                hout[(long)row * NDIM + nt * 16 + l16] = v;
                s += v; qs += v * v;
            }
        }
        s += __shfl_xor(s, 16);  s += __shfl_xor(s, 32);
        qs += __shfl_xor(qs, 16); qs += __shfl_xor(qs, 32);
        if (nt == 2 * q || nt == 2 * q + 1) {
            redS[w][nt * 16 + l16] = s;
            redQ[w][nt * 16 + l16] = qs;
        }
    }
    __syncthreads();
    if (tid < NDIM) {
        atomicAdd(&stats[cp + tid], redS[0][tid] + redS[1][tid] + redS[2][tid] + redS[3][tid]);
    } else {
        int c = tid - NDIM;
        atomicAdd(&stats[cp + NDIM + c], redQ[0][c] + redQ[1][c] + redQ[2][c] + redQ[3][c]);
    }
}

// ---------------------------------------------------------------------------
// K6: out = relu(BN2(h2)) -> output dtype
// ---------------------------------------------------------------------------
__global__ __launch_bounds__(256) void bn2_out_kernel(
    const float* __restrict__ h2, const float* __restrict__ statsIn,
    const void* __restrict__ g, const void* __restrict__ beta,
    void* __restrict__ out, int M, const int* __restrict__ flag) {
    const bool bf = (*flag != 0);
    __shared__ float scaleL[NDIM];
    __shared__ float shiftL[NDIM];
    const int tid = threadIdx.x;
    if (tid < NDIM) {
        float s = 0.f, qv = 0.f;
#pragma unroll 4
        for (int c = 0; c < NSPLIT; ++c) {
            s += statsIn[c * 256 + tid];
            qv += statsIn[c * 256 + NDIM + tid];
        }
        float invM = 1.0f / (float)M;
        float mean = s * invM;
        float var = fmaxf(qv * invM - mean * mean, 0.0f) + 1e-5f;
        float gv = bf ? bf2f(((const u16*)g)[tid]) : ((const float*)g)[tid];
        float bv = bf ? bf2f(((const u16*)beta)[tid]) : ((const float*)beta)[tid];
        float sc = gv * rsqrtf(var);
        scaleL[tid] = sc;
        shiftL[tid] = bv - mean * sc;
    }
    __syncthreads();

    const int n4 = M * NDIM / 4;
    for (int i = blockIdx.x * 256 + tid; i < n4; i += gridDim.x * 256) {
        int c = (i & 31) * 4;
        f32x4 hv = __builtin_nontemporal_load((const f32x4*)(h2 + (long)i * 4));
        float o0 = fmaxf(hv[0] * scaleL[c + 0] + shiftL[c + 0], 0.0f);
        float o1 = fmaxf(hv[1] * scaleL[c + 1] + shiftL[c + 1], 0.0f);
        float o2 = fmaxf(hv[2] * scaleL[c + 2] + shiftL[c + 2], 0.0f);
        float o3 = fmaxf(hv[3] * scaleL[c + 3] + shiftL[c + 3], 0.0f);
        if (bf) {
            u16x4 o;
            o.x = f2bf(o0); o.y = f2bf(o1); o.z = f2bf(o2); o.w = f2bf(o3);
            __builtin_nontemporal_store(o, (u16x4*)((u16*)out + (long)i * 4));
        } else {
            f32x4 o = (f32x4){o0, o1, o2, o3};
            __builtin_nontemporal_store(o, (f32x4*)((float*)out + (long)i * 4));
        }
    }
}

extern "C" void kernel_launch(void* const* d_in, const int* in_sizes, int n_in,
                              void* d_out, int out_size, void* d_ws, size_t ws_size,
                              hipStream_t stream) {
    const void* x         = d_in[0];
    const int*  ei        = (const int*)d_in[1];
    const void* edge_attr = d_in[2];
    const void* eps_p     = d_in[3];
    const void* We        = d_in[4];
    const void* be        = d_in[5];
    const void* W1        = d_in[6];
    const void* b1        = d_in[7];
    const void* g1        = d_in[8];
    const void* beta1     = d_in[9];
    const void* W2        = d_in[10];
    const void* b2        = d_in[11];
    const void* g2        = d_in[12];
    const void* beta2     = d_in[13];

    int N = in_sizes[0] / NDIM;                // 50000
    int E = in_sizes[1] / 2;                   // 800000
    const size_t nd = (size_t)N * NDIM;

    float* agg    = (float*)d_ws;              // [nd]; reused as h2
    float* h1     = agg + nd;                  // [nd]
    float* stats1 = h1 + nd;                   // [NSPLIT*256]
    float* stats2 = stats1 + NSPLIT * 256;     // [NSPLIT*256]
    int*   flag   = (int*)(stats2 + NSPLIT * 256); // [4]
    u16*   WeT    = (u16*)(flag + 4);          // [128*32]
    u16*   W1T    = WeT + NDIM * EDIM;         // [128*128]
    u16*   W2T    = W1T + NDIM * NDIM;         // [128*128]
    int*   tsum   = (int*)(W2T + NDIM * NDIM); // [1024]
    float* h2     = agg;                       // reuse

    // CSR scratch overlaid on h1 (dead before gemm1 writes h1)
    int2* pairs   = (int2*)h1;                 // [E]
    int* cnt      = (int*)(pairs + E);         // [N]
    int* row_ptr  = cnt + N;                   // [N+1]
    int* rank     = row_ptr + N + 1;           // [E]

    hipMemsetAsync(stats1, 0, 2 * NSPLIT * 256 * sizeof(float), stream);
    hipMemsetAsync(cnt, 0, (size_t)N * sizeof(int), stream);

    const int eblk = (E + 255) / 256;
    const int ntile = (N + 1023) / 1024;
    hist_kernel<<<eblk, 256, 0, stream>>>(ei, cnt, rank, E);
    scan_sums<<<ntile, 256, 0, stream>>>(cnt, tsum, N);
    scan_down<<<ntile, 256, 0, stream>>>(cnt, tsum, row_ptr, N, E);
    scatter_kernel<<<eblk, 256, 0, stream>>>(ei, row_ptr, rank, pairs, E);

    prep_kernel<<<64, 256, 0, stream>>>(x, We, W1, W2, WeT, W1T, W2T, flag);

    agg_kernel<<<2048, 256, 0, stream>>>(row_ptr, pairs, edge_attr, x,
                                         WeT, be, agg, N, flag);

    const int nblk = (N + 63) / 64;
    gemm1_kernel<<<nblk, 256, 0, stream>>>(x, agg, eps_p, W1T, b1, h1, stats1, N, flag);
    gemm2_kernel<<<nblk, 256, 0, stream>>>(h1, stats1, g1, beta1, W2T, b2, h2, stats2, N, flag);
    bn2_out_kernel<<<2048, 256, 0, stream>>>(h2, stats2, g2, beta2, d_out, N, flag);
}